// Round 9
// baseline (34657.764 us; speedup 1.0000x reference)
//
#include <hip/hip_runtime.h>
#include <hip/hip_bf16.h>
#include <hip/hip_fp16.h>

// StrokeRecoveryModel: S=256 seq steps, B=64, E=1024, H=4, D=256, V=5.
// Round 14: R13 (lstm 256-block split) WORKED: 37.99 -> 34.31ms, confirming
// latency/occupancy-bound per-step kernels. Same mechanism applied to the
// attention K/V path: QK^T and PV previously issued 2B+1B scalar loads per
// thread (128B/wave) — now each thread handles 4 consecutive s (QK^T) or
// 4 consecutive d (PV), loading uint2 (4 fp16) + uint (4 e5m2) per step:
// 4x fewer load instructions, 512B/wave, same bytes, same decode math.
// Reduction = 8 partials/output in a 10.3KB LDS union (still 4 blocks/CU).
// Everything else byte-identical to R13 (absmax 0.00390625 proven).
// R5/R4 fallback paths retained.

#define S_LEN 256

// ---------------- slow-path (round-4) layout: proven to fit ----------------
#define OFF_H1    0
#define OFF_C1    65536
#define OFF_H2    131072
#define OFF_C2    196608
#define OFF_Q     262144
#define OFF_CR    327680
#define OFF_CX    393216
#define OFF_G1    458752
#define OFF_G2    720896
#define OFF_B1C   983040
#define OFF_B2C   987136
#define OFF_BQ    991232
#define OFF_BO    994304
#define OFF_BOUT  995328
#define OFF_FLAGS 995336
#define OFF_KT    995360
#define OFF_VB    (995360 + 16777216)
#define WS_FLOATS (995360ull + 2ull * 16777216ull)
#define WS_NEED   (WS_FLOATS * 4ull)

// ---------------- round-5 fast-path layout ----------------
#define FOFF_QV    262144
#define FOFF_CR    327680
#define FOFF_G1P   393216
#define FOFF_G2P   655360
#define FOFF_P     917504
#define FOFF_B1C   1966080
#define FOFF_B2C   1970176
#define FOFF_BQ    1974272
#define FOFF_BO    1977344
#define FOFF_BOUT  1978368
#define FOFF_FLAGS 1978376
#define FOFF_WEFF  1978400
#define FOFF_KT    6172704
#define FOFF_VB    22949920
#define FWS_FLOATS 39727136ull
#define FWS_NEED   (FWS_FLOATS * 4ull)

// ---------------- round-11/14 MFMA-path layout (floats) ----------------
#define NOFF_H1    0
#define NOFF_C1    65536
#define NOFF_H2    131072
#define NOFF_C2    196608
#define NOFF_H1HI  262144
#define NOFF_H1LO  294912
#define NOFF_H2HI  327680
#define NOFF_H2LO  360448
#define NOFF_CRHI  393216
#define NOFF_CRLO  425984
#define NOFF_Q     458752
#define NOFF_G1P   524288
#define NOFF_G2P   786432
#define NOFF_B1C   1048576
#define NOFF_B2C   1052672
#define NOFF_BQ    1056768
#define NOFF_BO    1059840
#define NOFF_BOUT  1060864
#define NOFF_FLAGS 1060872
#define NOFF_A1HI  1060896
#define NOFF_A1LO  3158048
#define NOFF_A2HI  5255200
#define NOFF_A2LO  7352352
#define NOFF_A3HI  9449504
#define NOFF_A3LO  11546656
#define NOFF_A5HI  13643808
#define NOFF_A5LO  15740960
#define NOFF_A6HI  17838112
#define NOFF_A6LO  19935264
#define NOFF_A4HI  22032416
#define NOFF_A4LO  22556704
#define NOFF_KTH   23080992
#define NOFF_KTL   31469600
#define NOFF_VBH   35663904
#define NOFF_VBL   44052512
#define NWS_FLOATS 48246816ull
#define NWS_NEED   (NWS_FLOATS * 4ull)   // 192,987,264 B (< 226.5 MB proven)

typedef unsigned int uint;
typedef unsigned short ushort;
typedef unsigned char uchar;

typedef __attribute__((ext_vector_type(8))) short short8v;   // 8 bf16 = 4 VGPR
typedef __attribute__((ext_vector_type(4))) float f32x4;

__device__ __forceinline__ float sigm(float x) { return 1.f / (1.f + __expf(-x)); }
__device__ __forceinline__ float bfl(uint u) { return __uint_as_float(u << 16); }
__device__ __forceinline__ float bfh(uint u) { return __uint_as_float(u & 0xffff0000u); }

// round-to-nearest-even fp32 -> bf16 bits
__device__ __forceinline__ ushort f2bf(float x) {
  uint u = __float_as_uint(x);
  return (ushort)((u + 0x7fffu + ((u >> 16) & 1u)) >> 16);
}
__device__ __forceinline__ float bf2f(ushort u) { return __uint_as_float(((uint)u) << 16); }

// fp16 bit helpers (hi/lo split storage for K/V)
__device__ __forceinline__ ushort h_bits(__half h) {
  ushort u; __builtin_memcpy(&u, &h, 2); return u;
}
__device__ __forceinline__ float h2f_bits(ushort u) {
  __half h; __builtin_memcpy(&h, &u, 2); return __half2float(h);
}

__device__ __forceinline__ f32x4 mfma16(short8v a, short8v b, f32x4 c) {
  return __builtin_amdgcn_mfma_f32_16x16x32_bf16(a, b, c, 0, 0, 0);
}

// flag-branched loads (wave-uniform flag => ~free)
__device__ __forceinline__ float4 ld4f(const void* p, size_t i, int bf) {
  if (bf) {
    uint2 u = *(const uint2*)((const ushort*)p + i);
    return make_float4(bfl(u.x), bfh(u.x), bfl(u.y), bfh(u.y));
  }
  return *(const float4*)((const float*)p + i);
}
__device__ __forceinline__ float ld1f(const void* p, size_t i, int bf) {
  if (bf) return __uint_as_float(((uint)((const ushort*)p)[i]) << 16);
  return ((const float*)p)[i];
}

// ---------------------------------------------------------------------------
// Shared-memory union for the fused kernels (max member: b = 10272 B)
// ---------------------------------------------------------------------------
union SharedU {
  struct { float lq[256]; float latt[256]; float p8[2048]; float red[8]; } b;
  float sg[4][32][17];
  float red2[40];
};

// ---------------------------------------------------------------------------
// Device phase bodies
// ---------------------------------------------------------------------------
__device__ __forceinline__ void do_qgemm(
    const ushort* h2h, const ushort* h2l, const ushort* A4h, const ushort* A4l,
    const float* bqF, float* qv, int unit, int t) {
  int nb = unit & 15, mhalf = unit >> 4;
  int l = t & 63, w = t >> 6;
  int nt = w & 3, mq = w >> 2;
  int col = l & 15, klane = l >> 4;
  int ntg = (nb << 2) + nt;
  const short8v* Xh = (const short8v*)h2h;
  const short8v* Xl = (const short8v*)h2l;
  const short8v* Bh = (const short8v*)A4h;
  const short8v* Bl = (const short8v*)A4l;
  size_t wbase = (size_t)(ntg << 5) * 64 + l;
  int m0 = (mhalf << 5) + (mq << 4) + col;
  f32x4 acc = {0.f, 0.f, 0.f, 0.f};
#pragma unroll 4
  for (int kt = 0; kt < 32; ++kt) {
    short8v bh = Bh[wbase + (kt << 6)];
    short8v bl = Bl[wbase + (kt << 6)];
    int ia = (m0 << 7) + (kt << 2) + klane;
    short8v a_h = Xh[ia], a_l = Xl[ia];
    acc = mfma16(a_h, bh, acc);
    acc = mfma16(a_l, bh, acc);
    acc = mfma16(a_h, bl, acc);
  }
  int n = (ntg << 4) + col;
  float bias = bqF[n];
#pragma unroll
  for (int r = 0; r < 4; ++r) {
    int m = (mhalf << 5) + (mq << 4) + (klane << 2) + r;
    qv[(m << 10) + n] = acc[r] + bias;
  }
}

// 512-thread out head; writes out[srow*64+b].
__device__ __forceinline__ void do_outhead(
    const float* h2, const void* wout, const int* flags, const float* boutF,
    float* out, int b, int srow, int t, float* red2) {
  int f13 = flags[13];
  float p[5] = {0.f, 0.f, 0.f, 0.f, 0.f};
  for (int e = t; e < 1024; e += 512) {
    float hv = h2[(b << 10) + e];
#pragma unroll
    for (int v = 0; v < 5; v++) p[v] += hv * ld1f(wout, (size_t)(v << 10) + e, f13);
  }
#pragma unroll
  for (int v = 0; v < 5; v++)
#pragma unroll
    for (int o = 32; o >= 1; o >>= 1) p[v] += __shfl_xor(p[v], o, 64);
  int l = t & 63, w = t >> 6;
  if (l == 0) {
#pragma unroll
    for (int v = 0; v < 5; v++) red2[w * 5 + v] = p[v];
  }
  __syncthreads();
  if (t < 5) {
    float a = boutF[t];
    for (int w2 = 0; w2 < 8; w2++) a += red2[w2 * 5 + t];
    if (t >= 2) a = sigm(a);
    out[(srow * 64 + b) * 5 + t] = a;
  }
}

// split K/V attention, 4-wide vectorized loads (uint2 fp16-hi + uint e5m2-lo),
// fp32 accumulate. QK^T: thread = (d-eighth, s-quad); PV: (s-eighth, d-quad).
__device__ __forceinline__ void do_attn(
    const float* qv,
    const ushort* KtH, const uchar* KtL, const ushort* VbH, const uchar* VbL,
    ushort* crh, ushort* crl, int p, int t, SharedU& su) {
  float* lq = su.b.lq;
  float* latt = su.b.latt;
  float* p8 = su.b.p8;
  float* red = su.b.red;
  int b = p >> 2, h = p & 3;
  if (t < 256) lq[t] = qv[(b << 10) + (h << 8) + t];
  __syncthreads();
  // ---- QK^T: s = 4*sq4+{0..3}, d in [de*32, de*32+32) ----
  {
    int sq4 = t & 63, de = t >> 6;
    const uint2* KH4 = (const uint2*)(KtH + (((size_t)p) << 16));
    const uint*  KL4 = (const uint*)(KtL + (((size_t)p) << 16));
    float a0 = 0.f, a1 = 0.f, a2 = 0.f, a3 = 0.f;
    int dbase = de << 5;
#pragma unroll 8
    for (int dd = 0; dd < 32; ++dd) {
      int d = dbase + dd;
      uint2 hh = KH4[(d << 6) + sq4];
      uint  ll = KL4[(d << 6) + sq4];
      float k0 = h2f_bits((ushort)hh.x) + h2f_bits((ushort)((ll & 0xffu) << 8));
      float k1 = h2f_bits((ushort)(hh.x >> 16)) + h2f_bits((ushort)(ll & 0xff00u));
      float k2 = h2f_bits((ushort)hh.y) + h2f_bits((ushort)((ll >> 8) & 0xff00u));
      float k3 = h2f_bits((ushort)(hh.y >> 16)) + h2f_bits((ushort)((ll >> 24) << 8));
      float qd = lq[d];
      a0 += qd * k0; a1 += qd * k1; a2 += qd * k2; a3 += qd * k3;
    }
    int sb = (de << 8) + (sq4 << 2);
    p8[sb + 0] = a0; p8[sb + 1] = a1; p8[sb + 2] = a2; p8[sb + 3] = a3;
  }
  __syncthreads();
  int si = t & 255;
  float sc = (p8[si] + p8[si + 256] + p8[si + 512] + p8[si + 768] +
              p8[si + 1024] + p8[si + 1280] + p8[si + 1536] + p8[si + 1792]) * 0.0625f;
  float mx = sc;
#pragma unroll
  for (int o = 32; o >= 1; o >>= 1) mx = fmaxf(mx, __shfl_xor(mx, o, 64));
  if ((t & 63) == 0) red[t >> 6] = mx;
  __syncthreads();
  mx = red[0];
#pragma unroll
  for (int i = 1; i < 8; ++i) mx = fmaxf(mx, red[i]);
  float e = __expf(sc - mx);
  float ssum = e;
#pragma unroll
  for (int o = 32; o >= 1; o >>= 1) ssum += __shfl_xor(ssum, o, 64);
  __syncthreads();
  if ((t & 63) == 0) red[t >> 6] = ssum;
  __syncthreads();
  ssum = (red[0] + red[1] + red[2] + red[3] + red[4] + red[5] + red[6] + red[7]) * 0.5f;
  if (t < 256) latt[t] = e / ssum;
  __syncthreads();
  // ---- PV: d = 4*dq4+{0..3}, s in [se*32, se*32+32) ----
  {
    int dq4 = t & 63, se = t >> 6;
    const uint2* VH4 = (const uint2*)(VbH + (((size_t)p) << 16));
    const uint*  VL4 = (const uint*)(VbL + (((size_t)p) << 16));
    float c0 = 0.f, c1 = 0.f, c2 = 0.f, c3 = 0.f;
    int sbase = se << 5;
#pragma unroll 8
    for (int ss3 = 0; ss3 < 32; ++ss3) {
      int s3 = sbase + ss3;
      uint2 hh = VH4[(s3 << 6) + dq4];
      uint  ll = VL4[(s3 << 6) + dq4];
      float v0 = h2f_bits((ushort)hh.x) + h2f_bits((ushort)((ll & 0xffu) << 8));
      float v1 = h2f_bits((ushort)(hh.x >> 16)) + h2f_bits((ushort)(ll & 0xff00u));
      float v2 = h2f_bits((ushort)hh.y) + h2f_bits((ushort)((ll >> 8) & 0xff00u));
      float v3 = h2f_bits((ushort)(hh.y >> 16)) + h2f_bits((ushort)((ll >> 24) << 8));
      float a = latt[s3];
      c0 += a * v0; c1 += a * v1; c2 += a * v2; c3 += a * v3;
    }
    __syncthreads();
    int db = (se << 8) + (dq4 << 2);
    p8[db + 0] = c0; p8[db + 1] = c1; p8[db + 2] = c2; p8[db + 3] = c3;
  }
  __syncthreads();
  if (t < 256) {
    float v = p8[t] + p8[t + 256] + p8[t + 512] + p8[t + 768] +
              p8[t + 1024] + p8[t + 1280] + p8[t + 1536] + p8[t + 1792];
    int idx = (b << 10) + (h << 8) + t;
    ushort hu = f2bf(v);
    crh[idx] = hu;
    crl[idx] = f2bf(v - bf2f(hu));
  }
}

__device__ __forceinline__ void gg_pass(
    const ushort* xh, const ushort* xl, const ushort* Ah, const ushort* Al,
    size_t wbase, int m0, f32x4& acc0, f32x4& acc1) {
  const short8v* Xh = (const short8v*)xh;
  const short8v* Xl = (const short8v*)xl;
  const short8v* Bh = (const short8v*)Ah;
  const short8v* Bl = (const short8v*)Al;
  int klane = ((int)(wbase & 63)) >> 4;
#pragma unroll 4
  for (int kt = 0; kt < 32; ++kt) {
    short8v bh = Bh[wbase + (kt << 6)];
    short8v bl = Bl[wbase + (kt << 6)];
    int iaa = (m0 << 7) + (kt << 2) + klane;
    short8v ah0 = Xh[iaa], al0 = Xl[iaa];
    short8v ah1 = Xh[iaa + 2048], al1 = Xl[iaa + 2048];
    acc0 = mfma16(ah0, bh, acc0); acc0 = mfma16(al0, bh, acc0); acc0 = mfma16(ah0, bl, acc0);
    acc1 = mfma16(ah1, bh, acc1); acc1 = mfma16(al1, bh, acc1); acc1 = mfma16(ah1, bl, acc1);
  }
}

__device__ __forceinline__ void do_gate(
    const ushort* h2h, const ushort* h2l, const ushort* h1h, const ushort* h1l,
    const ushort* W1h, const ushort* W1l, const ushort* W2h, const ushort* W2l,
    const float* bias, float* gout, int two_pass, int b2, int t) {
  int l = t & 63, w = t >> 6;
  int nt = w & 3, mh = w >> 2;
  int col = l & 15;
  f32x4 acc0 = {0.f, 0.f, 0.f, 0.f}, acc1 = {0.f, 0.f, 0.f, 0.f};
  int ntg = (b2 << 2) + nt;
  size_t wbase = (size_t)(ntg << 5) * 64 + l;
  int m0 = (mh << 5) + col;
  gg_pass(h2h, h2l, W1h, W1l, wbase, m0, acc0, acc1);
  if (two_pass) gg_pass(h1h, h1l, W2h, W2l, wbase, m0, acc0, acc1);
  int n = (ntg << 4) + col;
  float bv = bias[n];
  int klane = l >> 4;
#pragma unroll
  for (int r = 0; r < 4; ++r) {
    int mrow = (klane << 2) + r;
    gout[(size_t)((mh << 5) + mrow) * 4096 + n] = acc0[r] + bv;
    gout[(size_t)((mh << 5) + 16 + mrow) * 4096 + n] = acc1[r] + bv;
  }
}

// 256-thread lstm block — one (j-tile, m-quarter); 4 waves = 4 gates.
__device__ __forceinline__ void do_lstm256(
    const ushort* xh, const ushort* xl, const ushort* Wh, const ushort* Wl,
    const float* gpart, float* cbuf, float* hbuf, ushort* hhi, ushort* hlo,
    int unit, int t, float sg[4][16][17]) {
  int jt = unit & 63, mq4 = unit >> 6;       // 0..63, 0..3
  int l = t & 63, g = t >> 6;                // 4 waves, one gate each
  int col = l & 15, klane = l >> 4;
  int ntg = (g << 6) + jt;
  const short8v* Xh = (const short8v*)xh;
  const short8v* Xl = (const short8v*)xl;
  const short8v* Bh = (const short8v*)Wh;
  const short8v* Bl = (const short8v*)Wl;
  size_t wbase = (size_t)(ntg << 5) * 64 + l;
  int m0 = (mq4 << 4) + col;
  f32x4 acc = {0.f, 0.f, 0.f, 0.f};
#pragma unroll 4
  for (int kt = 0; kt < 32; ++kt) {
    short8v bh = Bh[wbase + (kt << 6)];
    short8v bl = Bl[wbase + (kt << 6)];
    int ia = (m0 << 7) + (kt << 2) + klane;
    short8v a_h = Xh[ia], a_l = Xl[ia];
    acc = mfma16(a_h, bh, acc);
    acc = mfma16(a_l, bh, acc);
    acc = mfma16(a_h, bl, acc);
  }
#pragma unroll
  for (int r = 0; r < 4; ++r)
    sg[g][(klane << 2) + r][col] = acc[r];
  __syncthreads();
  int ml = t >> 4, j = t & 15;               // 16 m x 16 j = 256 threads
  int m = (mq4 << 4) + ml;
  int jj = (jt << 4) + j;
  size_t gb = (size_t)m * 4096 + jj;
  float gi = sg[0][ml][j] + gpart[gb];
  float gf = sg[1][ml][j] + gpart[gb + 1024];
  float gg = sg[2][ml][j] + gpart[gb + 2048];
  float go = sg[3][ml][j] + gpart[gb + 3072];
  gi = sigm(gi); gf = sigm(gf); gg = tanhf(gg); go = sigm(go);
  int hb = (m << 10) + jj;
  float c = gf * cbuf[hb] + gi * gg;
  cbuf[hb] = c;
  float hval = go * tanhf(c);
  hbuf[hb] = hval;
  ushort hu = f2bf(hval);
  hhi[hb] = hu;
  hlo[hb] = f2bf(hval - bf2f(hu));
}

// ---------------------------------------------------------------------------
// dtype detector + bias canonicalization (shared by all paths)
// ---------------------------------------------------------------------------
struct Ptrs { const void* p[15]; int n[15]; };

__global__ __launch_bounds__(64) void detect_kernel(Ptrs pp, int* flags) {
  int lane = threadIdx.x;
  for (int i = 0; i < 15; i++) {
    int nw = pp.n[i] / 2;
    if (nw > 64) nw = 64;
    int pass = 0;
    if (lane < nw) {
      uint w = ((const uint*)pp.p[i])[lane];
      uint ex = (w >> 7) & 0xFFu;
      pass = (ex >= 96u && ex <= 134u) ? 1 : 0;
    }
    unsigned long long bal = __ballot(pass);
    int cnt = __popcll(bal);
    if (lane == 0) flags[i] = (cnt * 4 >= nw * 3) ? 1 : 0;
  }
}

__global__ __launch_bounds__(256) void bias_cvt(
    const void* bqkv, const void* bo, const void* bih1, const void* bhh1,
    const void* bih2, const void* bhh2, const void* bout, const int* __restrict__ flags,
    float* bqF, float* boF, float* b1c, float* b2c, float* boutF) {
  int j = blockIdx.x * 256 + threadIdx.x;
  if (j < 3072) bqF[j] = ld1f(bqkv, j, flags[2]);
  if (j < 1024) boF[j] = ld1f(bo, j, flags[4]);
  if (j < 4096) {
    b1c[j] = ld1f(bih1, j, flags[7]) + ld1f(bhh1, j, flags[8]);
    b2c[j] = ld1f(bih2, j, flags[11]) + ld1f(bhh2, j, flags[12]);
  }
  if (j < 5) boutF[j] = ld1f(bout, j, flags[14]);
}

// b1c[j] += sum_m wih1[j,1024+m] * b_o[m]   (o-proj bias fold)
__global__ __launch_bounds__(256) void bias_fold(
    const void* __restrict__ wih1, const int* __restrict__ flags,
    const float* __restrict__ boF, float* __restrict__ b1c) {
  __shared__ float lbo[1024];
  int t = threadIdx.x;
  ((float4*)lbo)[t] = ((const float4*)boF)[t];
  __syncthreads();
  int f5 = flags[5];
  int j = blockIdx.x * 256 + t;
  size_t r = (size_t)j * 2048 + 1024;
  float acc = 0.f;
#pragma unroll 4
  for (int i = 0; i < 256; i++) {
    float4 w4 = ld4f(wih1, r + 4 * i, f5);
    float4 x4 = ((float4*)lbo)[i];
    acc += w4.x * x4.x + w4.y * x4.y + w4.z * x4.z + w4.w * x4.w;
  }
  b1c[j] += acc;
}

// ---------------------------------------------------------------------------
// KV GEMM (one-time, fp32 math): C[16384,2048] = cnn @ w_qkv[1024:3072]^T
// (+bias). mode=1: scatter fp16-hi + e5m2-lo; mode=0: fp32 (fallbacks).
// ---------------------------------------------------------------------------
__global__ __launch_bounds__(256) void kv_gemm(
    const void* __restrict__ A, const void* __restrict__ Wq,
    const int* __restrict__ flags, const float* __restrict__ bqF,
    void* __restrict__ KtvH, void* __restrict__ VbvH,
    uchar* __restrict__ KtL, uchar* __restrict__ VbL, int mode) {
  __shared__ float sA[16][65];
  __shared__ float sB[16][65];
  int f0 = flags[0], f1 = flags[1];
  int m0 = blockIdx.y << 6;
  int n0 = blockIdx.x << 6;
  int t = threadIdx.x;
  int lm = t >> 2, lk = (t & 3) << 2;
  int tx = t & 15, ty = t >> 4;
  float acc[4][4] = {};
  for (int k0 = 0; k0 < 1024; k0 += 16) {
    float4 a4 = ld4f(A, (size_t)(m0 + lm) * 1024 + k0 + lk, f0);
    float4 b4 = ld4f(Wq, (size_t)(1024 + n0 + lm) * 1024 + k0 + lk, f1);
    __syncthreads();
    sA[lk + 0][lm] = a4.x; sA[lk + 1][lm] = a4.y; sA[lk + 2][lm] = a4.z; sA[lk + 3][lm] = a4.w;
    sB[lk + 0][lm] = b4.x; sB[lk + 1][lm] = b4.y; sB[lk + 2][lm] = b4.z; sB[lk + 3][lm] = b4.w;
    __syncthreads();
#pragma unroll
    for (int k = 0; k < 16; k++) {
      float av[4], bv[4];
#pragma unroll
      for (int i = 0; i < 4; i++) av[i] = sA[k][ty * 4 + i];
#pragma unroll
      for (int j = 0; j < 4; j++) bv[j] = sB[k][tx * 4 + j];
#pragma unroll
      for (int i = 0; i < 4; i++)
#pragma unroll
        for (int j = 0; j < 4; j++) acc[i][j] += av[i] * bv[j];
    }
  }
#pragma unroll
  for (int i = 0; i < 4; i++) {
    int m = m0 + ty * 4 + i;
    int s = m >> 6, b = m & 63;
#pragma unroll
    for (int j = 0; j < 4; j++) {
      int n = n0 + tx * 4 + j;
      float v = acc[i][j];
      if (n < 1024) {
        int h = n >> 8, d = n & 255;
        v += bqF[1024 + n];
        size_t idx = ((size_t)(((b << 2) | h) << 8 | d) << 8) | s;
        if (mode) {
          __half hh = __float2half(v);
          float rr = v - __half2float(hh);
          ushort rb = h_bits(__float2half(rr));
          ((ushort*)KtvH)[idx] = h_bits(hh);
          KtL[idx] = (uchar)(((uint)rb + 0x80u) >> 8);
        } else {
          ((float*)KtvH)[idx] = v;
        }
      } else {
        int nn = n - 1024;
        int h = nn >> 8, d = nn & 255;
        v += bqF[2048 + nn];
        size_t idx = ((size_t)(((b << 2) | h) << 8 | s) << 8) | d;
        if (mode) {
          __half hh = __float2half(v);
          float rr = v - __half2float(hh);
          ushort rb = h_bits(__float2half(rr));
          ((ushort*)VbvH)[idx] = h_bits(hh);
          VbL[idx] = (uchar)(((uint)rb + 0x80u) >> 8);
        } else {
          ((float*)VbvH)[idx] = v;
        }
      }
    }
  }
}

// ---------------------------------------------------------------------------
// Weff[4096,1024] = wih1[:,1024:] @ w_o   (fp32 out, one-time)
// ---------------------------------------------------------------------------
__global__ __launch_bounds__(256) void weff_gemm(
    const void* __restrict__ wih1, const void* __restrict__ wo,
    const int* __restrict__ flags, float* __restrict__ Weff) {
  __shared__ float sA[16][65];
  __shared__ float sB[16][65];
  int f5 = flags[5], f3 = flags[3];
  int m0 = blockIdx.y << 6;
  int n0 = blockIdx.x << 6;
  int t = threadIdx.x;
  int lm = t >> 2, lk = (t & 3) << 2;
  int kk = t >> 4, nn2 = (t & 15) << 2;
  int tx = t & 15, ty = t >> 4;
  float acc[4][4] = {};
  for (int k0 = 0; k0 < 1024; k0 += 16) {
    float4 a4 = ld4f(wih1, (size_t)(m0 + lm) * 2048 + 1024 + k0 + lk, f5);
    float4 b4 = ld4f(wo, (size_t)(k0 + kk) * 1024 + n0 + nn2, f3);
    __syncthreads();
    sA[lk + 0][lm] = a4.x; sA[lk + 1][lm] = a4.y; sA[lk + 2][lm] = a4.z; sA[lk + 3][lm] = a4.w;
    sB[kk][nn2 + 0] = b4.x; sB[kk][nn2 + 1] = b4.y; sB[kk][nn2 + 2] = b4.z; sB[kk][nn2 + 3] = b4.w;
    __syncthreads();
#pragma unroll
    for (int k = 0; k < 16; k++) {
      float av[4], bv[4];
#pragma unroll
      for (int i = 0; i < 4; i++) av[i] = sA[k][ty * 4 + i];
#pragma unroll
      for (int j = 0; j < 4; j++) bv[j] = sB[k][tx * 4 + j];
#pragma unroll
      for (int i = 0; i < 4; i++)
#pragma unroll
        for (int j = 0; j < 4; j++) acc[i][j] += av[i] * bv[j];
    }
  }
#pragma unroll
  for (int i = 0; i < 4; i++)
#pragma unroll
    for (int j = 0; j < 4; j++)
      Weff[(size_t)(m0 + ty * 4 + i) * 1024 + n0 + tx * 4 + j] = acc[i][j];
}

// ---------------------------------------------------------------------------
// weight hi/lo split + MFMA-fragment shuffle
// ---------------------------------------------------------------------------
__global__ __launch_bounds__(256) void wconv_kernel(
    const void* __restrict__ src, const int* __restrict__ flags, int fidx,
    int rs, int co, int ntiles, ushort* __restrict__ dh, ushort* __restrict__ dl) {
  int gid = blockIdx.x * 256 + threadIdx.x;
  int tile = gid >> 6, l = gid & 63;
  if (tile >= ntiles) return;
  int kt = tile & 31, nt = tile >> 5;
  int n = (nt << 4) + (l & 15);
  int k = (kt << 5) + ((l >> 4) << 3);
  int bf = (fidx >= 0) ? flags[fidx] : 0;
  size_t base = (size_t)n * rs + co + k;
  float v[8];
  if (!bf) {
    float4 x0 = *(const float4*)((const float*)src + base);
    float4 x1 = *(const float4*)((const float*)src + base + 4);
    v[0] = x0.x; v[1] = x0.y; v[2] = x0.z; v[3] = x0.w;
    v[4] = x1.x; v[5] = x1.y; v[6] = x1.z; v[7] = x1.w;
  } else {
#pragma unroll
    for (int j = 0; j < 8; ++j) v[j] = ld1f(src, base + j, 1);
  }
  short8v hv, lv;
#pragma unroll
  for (int j = 0; j < 8; ++j) {
    ushort hu = f2bf(v[j]);
    hv[j] = (short)hu;
    lv[j] = (short)f2bf(v[j] - bf2f(hu));
  }
  size_t o = ((size_t)tile << 6) + l;
  ((short8v*)dh)[o] = hv;
  ((short8v*)dl)[o] = lv;
}

// ---------------------------------------------------------------------------
// Fast-path per-step kernels (R13 structure; attn loads 4x vectorized)
// ---------------------------------------------------------------------------
__global__ __launch_bounds__(512) void qhead_kernel(
    const float* __restrict__ h2, const ushort* __restrict__ h2h, const ushort* __restrict__ h2l,
    const ushort* __restrict__ A4h, const ushort* __restrict__ A4l,
    const void* __restrict__ wout, const int* __restrict__ flags,
    const float* __restrict__ bqF, const float* __restrict__ boutF,
    float* __restrict__ qv, float* __restrict__ out, int s) {
  __shared__ SharedU su;
  int bi = blockIdx.x, t = threadIdx.x;
  if (bi < 32) {
    do_qgemm(h2h, h2l, A4h, A4l, bqF, qv, bi, t);
  } else {
    if (s == 0) return;
    do_outhead(h2, wout, flags, boutF, out, bi - 32, s - 1, t, su.red2);
  }
}

__global__ __launch_bounds__(512) void mega_kernel(
    const float* __restrict__ qv,
    const ushort* __restrict__ KtH, const uchar* __restrict__ KtL,
    const ushort* __restrict__ VbH, const uchar* __restrict__ VbL,
    const ushort* __restrict__ h1h, const ushort* __restrict__ h1l,
    const ushort* __restrict__ h2h, const ushort* __restrict__ h2l,
    const ushort* __restrict__ A1h, const ushort* __restrict__ A1l,
    const ushort* __restrict__ A2h, const ushort* __restrict__ A2l,
    const ushort* __restrict__ A3h, const ushort* __restrict__ A3l,
    const float* __restrict__ b1c, const float* __restrict__ b2c,
    ushort* __restrict__ crh, ushort* __restrict__ crl,
    float* __restrict__ g1p, float* __restrict__ g2p) {
  __shared__ SharedU su;
  int bi = blockIdx.x, t = threadIdx.x;
  if (bi < 256) {
    do_attn(qv, KtH, KtL, VbH, VbL, crh, crl, bi, t, su);
  } else if (bi < 320) {
    do_gate(h2h, h2l, h1h, h1l, A1h, A1l, A2h, A2l, b1c, g1p, 1, bi - 256, t);
  } else {
    do_gate(h2h, h2l, h1h, h1l, A3h, A3l, A3h, A3l, b2c, g2p, 0, bi - 320, t);
  }
}

// 256 blocks x 256 threads — full-chip coverage.
__global__ __launch_bounds__(256) void lstm_fused(
    const ushort* __restrict__ xh, const ushort* __restrict__ xl,
    const ushort* __restrict__ Wh, const ushort* __restrict__ Wl,
    const float* __restrict__ gpart, float* __restrict__ cbuf,
    float* __restrict__ hbuf, ushort* __restrict__ hhi, ushort* __restrict__ hlo) {
  __shared__ float sg[4][16][17];
  do_lstm256(xh, xl, Wh, Wl, gpart, cbuf, hbuf, hhi, hlo, blockIdx.x, threadIdx.x, sg);
}

// final output head (256-thr variant, used after loops)
__global__ __launch_bounds__(256) void outhead_kernel(
    const float* __restrict__ h2, const void* __restrict__ wout,
    const int* __restrict__ flags, const float* __restrict__ boutF,
    float* __restrict__ out, int row) {
  __shared__ float smem[1280];
  int b = blockIdx.x, t = threadIdx.x;
  int f13 = flags[13];
  float p[5] = {0.f, 0.f, 0.f, 0.f, 0.f};
#pragma unroll
  for (int k2 = 0; k2 < 4; k2++) {
    float hv = h2[(b << 10) + t + (k2 << 8)];
#pragma unroll
    for (int v = 0; v < 5; v++)
      p[v] += hv * ld1f(wout, (size_t)(v << 10) + t + (k2 << 8), f13);
  }
#pragma unroll
  for (int v = 0; v < 5; v++) smem[v * 256 + t] = p[v];
  __syncthreads();
  if (t < 5) {
    float acc = boutF[t];
    for (int i = 0; i < 256; i++) acc += smem[t * 256 + i];
    if (t >= 2) acc = sigm(acc);
    out[(row * 64 + b) * 5 + t] = acc;
  }
}

// ========================= SLOW PATHS (round-4/5, proven) ==================
__global__ __launch_bounds__(256) void p1_fast(
    const float* __restrict__ h1, const float* __restrict__ h2,
    const void* __restrict__ wih1, const void* __restrict__ whh1,
    const void* __restrict__ whh2, const void* __restrict__ wqkv,
    const void* __restrict__ wout, const int* __restrict__ flags,
    const float* __restrict__ b1c, const float* __restrict__ b2c,
    const float* __restrict__ bqF, const float* __restrict__ boutF,
    float* __restrict__ g1p, float* __restrict__ g2p,
    float* __restrict__ qv, float* __restrict__ out, int s) {
  __shared__ __align__(16) float sX[32][68];
  __shared__ __align__(16) float sW[32][68];
  int bi = blockIdx.x, t = threadIdx.x;

  if (bi >= 144) {
    if (s == 0) return;
    float* smem = &sX[0][0];
    int f13 = flags[13];
    int b = bi - 144;
    float p[5] = {0.f, 0.f, 0.f, 0.f, 0.f};
#pragma unroll
    for (int k2 = 0; k2 < 4; k2++) {
      float hv = h2[(b << 10) + t + (k2 << 8)];
#pragma unroll
      for (int v = 0; v < 5; v++)
        p[v] += hv * ld1f(wout, (size_t)(v << 10) + t + (k2 << 8), f13);
    }
#pragma unroll
    for (int v = 0; v < 5; v++) smem[v * 256 + t] = p[v];
    __syncthreads();
    if (t < 5) {
      float acc = boutF[t];
      for (int i = 0; i < 256; i++) acc += smem[t * 256 + i];
      if (t >= 2) acc = sigm(acc);
      out[((s - 1) * 64 + b) * 5 + t] = acc;
    }
    return;
  }

  int lm = t >> 2, lk8 = (t & 3) << 3;
  int tx = t & 15, ty = t >> 4;
  float acc[4][4] = {};

  int kind = (bi < 64) ? 0 : (bi < 128) ? 1 : 2;
  int n0 = (kind == 0) ? (bi << 6) : (kind == 1) ? ((bi - 64) << 6) : ((bi - 128) << 6);
  int Ktot = (kind == 0) ? 2048 : 1024;

  for (int k0 = 0; k0 < Ktot; k0 += 32) {
    const float* xs;
    const void* Wm;
    size_t wstride;
    int koff, bf;
    if (kind == 0) {
      if (k0 < 1024) { xs = h2; Wm = wih1; wstride = 2048; koff = k0; bf = flags[5]; }
      else           { xs = h1; Wm = whh1; wstride = 1024; koff = k0 - 1024; bf = flags[6]; }
    } else if (kind == 1) { xs = h2; Wm = whh2; wstride = 1024; koff = k0; bf = flags[10]; }
    else                  { xs = h2; Wm = wqkv; wstride = 1024; koff = k0; bf = flags[1]; }

    float4 xa = *(const float4*)(xs + (lm << 10) + koff + lk8);
    float4 xb = *(const float4*)(xs + (lm << 10) + koff + lk8 + 4);
    float4 wa = ld4f(Wm, (size_t)(n0 + lm) * wstride + koff + lk8, bf);
    float4 wb = ld4f(Wm, (size_t)(n0 + lm) * wstride + koff + lk8 + 4, bf);
    __syncthreads();
    sX[lk8 + 0][lm] = xa.x; sX[lk8 + 1][lm] = xa.y; sX[lk8 + 2][lm] = xa.z; sX[lk8 + 3][lm] = xa.w;
    sX[lk8 + 4][lm] = xb.x; sX[lk8 + 5][lm] = xb.y; sX[lk8 + 6][lm] = xb.z; sX[lk8 + 7][lm] = xb.w;
    sW[lk8 + 0][lm] = wa.x; sW[lk8 + 1][lm] = wa.y; sW[lk8 + 2][lm] = wa.z; sW[lk8 + 3][lm] = wa.w;
    sW[lk8 + 4][lm] = wb.x; sW[lk8 + 5][lm] = wb.y; sW[lk8 + 6][lm] = wb.z; sW[lk8 + 7][lm] = wb.w;
    __syncthreads();
#pragma unroll
    for (int k = 0; k < 32; k++) {
      float4 av = *(const float4*)&sX[k][ty << 2];
      float4 bv = *(const float4*)&sW[k][tx << 2];
      acc[0][0] += av.x * bv.x; acc[0][1] += av.x * bv.y; acc[0][2] += av.x * bv.z; acc[0][3] += av.x * bv.w;
      acc[1][0] += av.y * bv.x; acc[1][1] += av.y * bv.y; acc[1][2] += av.y * bv.z; acc[1][3] += av.y * bv.w;
      acc[2][0] += av.z * bv.x; acc[2][1] += av.z * bv.y; acc[2][2] += av.z * bv.z; acc[2][3] += av.z * bv.w;
      acc[3][0] += av.w * bv.x; acc[3][1] += av.w * bv.y; acc[3][2] += av.w * bv.z; acc[3][3] += av.w * bv.w;
    }
  }

  int col = n0 + (tx << 2);
  if (kind == 0) {
    float4 bias = *(const float4*)(b1c + col);
#pragma unroll
    for (int i = 0; i < 4; i++) {
      int b = (ty << 2) + i;
      *(float4*)(g1p + (b << 12) + col) =
          make_float4(acc[i][0] + bias.x, acc[i][1] + bias.y, acc[i][2] + bias.z, acc[i][3] + bias.w);
    }
  } else if (kind == 1) {
    float4 bias = *(const float4*)(b2c + col);
#pragma unroll
    for (int i = 0; i < 4; i++) {
      int b = (ty << 2) + i;
      *(float4*)(g2p + (b << 12) + col) =
          make_float4(acc[i][0] + bias.x, acc[i][1] + bias.y, acc[i][2] + bias.z, acc[i][3] + bias.w);
    }
  } else {
    float4 bias = *(const float4*)(bqF + col);
#pragma unroll
    for (int i = 0; i < 4; i++) {
      int b = (ty << 2) + i;
      *(float4*)(qv + (b << 10) + col) =
          make_float4(acc[i][0] + bias.x, acc[i][1] + bias.y, acc[i][2] + bias.z, acc[i][3] + bias.w);
    }
  }
}

__global__ __launch_bounds__(256) void lstm_gemm(
    const float* __restrict__ x, const void* __restrict__ Wm,
    const int* __restrict__ flags, int fidx, float* __restrict__ P) {
  __shared__ __align__(16) float sX[32][68];
  __shared__ __align__(16) float sW[32][68];
  int bi = blockIdx.x, t = threadIdx.x;
  int ks = bi >> 6;
  int n0 = (bi & 63) << 6;
  int kbase = ks << 8;
  int bf = (fidx >= 0) ? flags[fidx] : 0;
  int lm = t >> 2, lk8 = (t & 3) << 3;
  int tx = t & 15, ty = t >> 4;
  float acc[4][4] = {};
  for (int kc = 0; kc < 256; kc += 32) {
    int koff = kbase + kc;
    float4 xa = *(const float4*)(x + (lm << 10) + koff + lk8);
    float4 xb = *(const float4*)(x + (lm << 10) + koff + lk8 + 4);
    float4 wa = ld4f(Wm, (size_t)(n0 + lm) * 1024 + koff + lk8, bf);
    float4 wb = ld4f(Wm, (size_t)(n0 + lm) * 1024 + koff + lk8 + 4, bf);
    __syncthreads();
    sX[lk8 + 0][lm] = xa.x; sX[lk8 + 1][lm] = xa.y; sX[lk8 + 2][lm] = xa.z; sX[lk8 + 3][lm] = xa.w;
    sX[lk8 + 4][lm] = xb.x; sX[lk8 + 5][lm] = xb.y; sX[lk8 + 6][lm] = xb.z; sX[lk8 + 7][lm] = xb.w;
    sW[lk8 + 0][lm] = wa.x; sW[lk8 + 1][lm] = wa.y; sW[lk8 + 2][lm] = wa.z; sW[lk8 + 3][lm] = wa.w;
    sW[lk8 + 4][lm] = wb.x; sW[lk8 + 5][lm] = wb.y; sW[lk8 + 6][lm] = wb.z; sW[lk8 + 7][lm] = wb.w;
    __syncthreads();
#pragma unroll
    for (int k = 0; k < 32; k++) {
      float4 av = *(const float4*)&sX[k][ty << 2];
      float4 bv = *(const float4*)&sW[k][tx << 2];
      acc[0][0] += av.x * bv.x; acc[0][1] += av.x * bv.y; acc[0][2] += av.x * bv.z; acc[0][3] += av.x * bv.w;
      acc[1][0] += av.y * bv.x; acc[1][1] += av.y * bv.y; acc[1][2] += av.y * bv.z; acc[1][3] += av.y * bv.w;
      acc[2][0] += av.z * bv.x; acc[2][1] += av.z * bv.y; acc[2][2] += av.z * bv.z; acc[2][3] += av.z * bv.w;
      acc[3][0] += av.w * bv.x; acc[3][1] += av.w * bv.y; acc[3][2] += av.w * bv.z; acc[3][3] += av.w * bv.w;
    }
  }
  int col = n0 + (tx << 2);
  float* Pk = P + ((size_t)ks << 18);
#pragma unroll
  for (int i = 0; i < 4; i++) {
    int b = (ty << 2) + i;
    *(float4*)(Pk + (b << 12) + col) = make_float4(acc[i][0], acc[i][1], acc[i][2], acc[i][3]);
  }
}

__global__ __launch_bounds__(256) void lstm_ew(
    const float* __restrict__ gp, const float* __restrict__ P,
    float* __restrict__ cbuf, float* __restrict__ hbuf) {
  int b = blockIdx.x >> 2;
  int j = ((blockIdx.x & 3) << 8) + threadIdx.x;
  int base = (b << 12) + j;
  float g[4];
#pragma unroll
  for (int gi = 0; gi < 4; gi++) {
    int idx = base + (gi << 10);
    g[gi] = gp[idx] + P[idx] + P[idx + (1 << 18)] + P[idx + (2 << 18)] + P[idx + (3 << 18)];
  }
  float gi_ = sigm(g[0]);
  float gf_ = sigm(g[1]);
  float gg_ = tanhf(g[2]);
  float go_ = sigm(g[3]);
  float c = gf_ * cbuf[(b << 10) + j] + gi_ * gg_;
  cbuf[(b << 10) + j] = c;
  hbuf[(b << 10) + j] = go_ * tanhf(c);
}

__global__ __launch_bounds__(256) void attn_kernel(
    const float* __restrict__ qbuf, const float* __restrict__ Kt,
    const float* __restrict__ Vb, float* __restrict__ cr) {
  __shared__ float lq[256];
  __shared__ float latt[256];
  __shared__ float red[8];
  int p = blockIdx.x, t = threadIdx.x;
  int b = p >> 2, h = p & 3;
  lq[t] = qbuf[(b << 10) + (h << 8) + t];
  __syncthreads();
  const float* Kp = Kt + ((size_t)p << 16);
  float sc = 0.f;
#pragma unroll 4
  for (int d = 0; d < 256; d++) sc += lq[d] * Kp[(d << 8) + t];
  sc *= 0.0625f;
  float m = sc;
#pragma unroll
  for (int o = 32; o >= 1; o >>= 1) m = fmaxf(m, __shfl_xor(m, o, 64));
  if ((t & 63) == 0) red[t >> 6] = m;
  __syncthreads();
  m = fmaxf(fmaxf(red[0], red[1]), fmaxf(red[2], red[3]));
  float e = __expf(sc - m);
  float ss = e;
#pragma unroll
  for (int o = 32; o >= 1; o >>= 1) ss += __shfl_xor(ss, o, 64);
  if ((t & 63) == 0) red[4 + (t >> 6)] = ss;
  __syncthreads();
  ss = red[4] + red[5] + red[6] + red[7];
  latt[t] = e / ss;
  __syncthreads();
  const float* Vp = Vb + ((size_t)p << 16);
  float cv = 0.f;
#pragma unroll 4
  for (int s2 = 0; s2 < 256; s2++) cv += latt[s2] * Vp[(s2 << 8) + t];
  cr[(b << 10) + (h << 8) + t] = cv;
}

__global__ __launch_bounds__(256) void p1_kernel(
    const float* __restrict__ h1, const float* __restrict__ h2,
    const void* __restrict__ wih1, const void* __restrict__ whh1,
    const void* __restrict__ whh2, const void* __restrict__ wqkv,
    const void* __restrict__ wout, const int* __restrict__ flags,
    const float* __restrict__ b1c, const float* __restrict__ b2c,
    const float* __restrict__ bqF, const float* __restrict__ boutF,
    float* __restrict__ g1p, float* __restrict__ g2p,
    float* __restrict__ qbuf, float* __restrict__ out, int s) {
  __shared__ float smem[2048];
  int bi = blockIdx.x, t = threadIdx.x;
  if (bi < 1024) {
    int f5 = flags[5], f6 = flags[6], f10 = flags[10];
    int b = bi & 63, jt = bi >> 6;
    float4* s2 = (float4*)smem;
    float4* s1 = (float4*)(smem + 1024);
    s2[t] = ((const float4*)(h2 + (b << 10)))[t];
    s1[t] = ((const float4*)(h1 + (b << 10)))[t];
    __syncthreads();
    int j = (jt << 8) + t;
    size_t ra = (size_t)j * 2048, rb = (size_t)j * 1024;
    float a1 = 0.f, a3 = 0.f;
#pragma unroll 2
    for (int i = 0; i < 256; i++) {
      float4 A4 = ld4f(wih1, ra + 4 * i, f5);
      float4 B4 = ld4f(whh1, rb + 4 * i, f6);
      float4 C4 = ld4f(whh2, rb + 4 * i, f10);
      float4 x2 = s2[i], x1 = s1[i];
      a1 += x2.x * A4.x + x2.y * A4.y + x2.z * A4.z + x2.w * A4.w;
      a1 += x1.x * B4.x + x1.y * B4.y + x1.z * B4.z + x1.w * B4.w;
      a3 += x2.x * C4.x + x2.y * C4.y + x2.z * C4.z + x2.w * C4.w;
    }
    g1p[(b << 12) + j] = a1 + b1c[j];
    g2p[(b << 12) + j] = a3 + b2c[j];
  } else if (bi < 1280) {
    int f1 = flags[1];
    int idx = bi - 1024;
    int b = idx & 63, dt = idx >> 6;
    float4* s2 = (float4*)smem;
    s2[t] = ((const float4*)(h2 + (b << 10)))[t];
    __syncthreads();
    int col = (dt << 8) + t;
    size_t r = (size_t)col * 1024;
    float acc = 0.f;
#pragma unroll 4
    for (int i = 0; i < 256; i++) {
      float4 w4 = ld4f(wqkv, r + 4 * i, f1);
      float4 x = s2[i];
      acc += x.x * w4.x + x.y * w4.y + x.z * w4.z + x.w * w4.w;
    }
    qbuf[(b << 10) + col] = acc + bqF[col];
  } else {
    if (s == 0) return;
    int f13 = flags[13];
    int b = bi - 1280;
    float p[5] = {0.f, 0.f, 0.f, 0.f, 0.f};
#pragma unroll
    for (int k2 = 0; k2 < 4; k2++) {
      float hv = h2[(b << 10) + t + (k2 << 8)];
#pragma unroll
      for (int v = 0; v < 5; v++)
        p[v] += hv * ld1f(wout, (size_t)(v << 10) + t + (k2 << 8), f13);
    }
#pragma unroll
    for (int v = 0; v < 5; v++) smem[v * 256 + t] = p[v];
    __syncthreads();
    if (t < 5) {
      float acc = boutF[t];
      for (int i = 0; i < 256; i++) acc += smem[t * 256 + i];
      if (t >= 2) acc = sigm(acc);
      out[((s - 1) * 64 + b) * 5 + t] = acc;
    }
  }
}

__global__ __launch_bounds__(256) void oproj_kernel(
    const float* __restrict__ cr, const void* __restrict__ wo,
    const int* __restrict__ flags, const float* __restrict__ boF,
    float* __restrict__ cx) {
  __shared__ float lx[1024];
  int idx = blockIdx.x, b = idx & 63, dt = idx >> 6, t = threadIdx.x;
  ((float4*)lx)[t] = ((const float4*)(cr + (b << 10)))[t];
  __syncthreads();
  int f3 = flags[3];
  int col = (dt << 8) + t;
  size_t r = (size_t)col * 1024;
  float acc = 0.f;
#pragma unroll 4
  for (int i = 0; i < 256; i++) {
    float4 w4 = ld4f(wo, r + 4 * i, f3);
    float4 x = ((float4*)lx)[i];
    acc += x.x * w4.x + x.y * w4.y + x.z * w4.z + x.w * w4.w;
  }
  cx[(b << 10) + col] = acc + boF[col];
}

__global__ __launch_bounds__(256) void lstm_kernel(
    const float* __restrict__ xin, const void* __restrict__ Wg,
    const int* __restrict__ flags, int fidx, int rowStride, int colOff,
    const float* __restrict__ gpart, float* __restrict__ cbuf,
    float* __restrict__ hbuf) {
  __shared__ float lx[1024];
  int b = blockIdx.x >> 2, j0 = (blockIdx.x & 3) << 8;
  int t = threadIdx.x;
  ((float4*)lx)[t] = ((const float4*)(xin + (b << 10)))[t];
  __syncthreads();
  int bf = flags[fidx];
  int j = j0 + t;
  float g[4];
#pragma unroll
  for (int gi = 0; gi < 4; gi++) {
    size_t r = (size_t)((gi << 10) + j) * rowStride + colOff;
    float acc = 0.f;
#pragma unroll 4
    for (int i = 0; i < 256; i++) {
      float4 w4 = ld4f(Wg, r + 4 * i, bf);
      float4 x = ((float4*)lx)[i];
      acc += x.x * w4.x + x.y * w4.y + x.z * w4.z + x.w * w4.w;
    }
    g[gi] = gpart[(b << 12) + (gi << 10) + j] + acc;
  }
  float gi_ = sigm(g[0]);
  float gf_ = sigm(g[1]);
  float gg_ = tanhf(g[2]);
  float go_ = sigm(g[3]);
  float c = gf_ * cbuf[(b << 10) + j] + gi_ * gg_;
  cbuf[(b << 10) + j] = c;
  hbuf[(b << 10) + j] = go_ * tanhf(c);
}

// ===========================================================================
extern "C" void kernel_launch(void* const* d_in, const int* in_sizes, int n_in,
                              void* d_out, int out_size, void* d_ws, size_t ws_size,
                              hipStream_t stream) {
  float* out = (float*)d_out;
  float* W = (float*)d_ws;

  Ptrs pp;
  for (int i = 0; i < 15; i++) { pp.p[i] = d_in[i]; pp.n[i] = in_sizes[i]; }

  if (ws_size >= NWS_NEED) {
    // ------- R14 MFMA path (R13 structure; attn 4x-vectorized loads) -------
    float* h1    = W + NOFF_H1;
    float* c1    = W + NOFF_C1;
    float* h2    = W + NOFF_H2;
    float* c2    = W + NOFF_C2;
    ushort* h1h  = (ushort*)(W + NOFF_H1HI);
    ushort* h1l  = (ushort*)(W + NOFF_H1LO);
    ushort* h2h  = (ushort*)(W + NOFF_H2HI);
    ushort* h2l  = (ushort*)(W + NOFF_H2LO);
    ushort* crh  = (ushort*)(W + NOFF_CRHI);
    ushort* crl  = (ushort*)(W + NOFF_CRLO);
    float* qv    = W + NOFF_Q;
    float* g1p   = W + NOFF_G1P;
    float* g2p   = W + NOFF_G2P;
    float* b1c   = W + NOFF_B1C;
    float* b2c   = W + NOFF_B2C;
    float* bqF   = W + NOFF_BQ;
    float* boF   = W + NOFF_BO;
    float* boutF = W + NOFF_BOUT;
    int*   flags = (int*)(W + NOFF_FLAGS);
    float* scratch = W + NOFF_A1HI;           // Weff fp32 staging (overwritten by A1 conv)
    ushort* A1h = (ushort*)(W + NOFF_A1HI);
    ushort* A1l = (ushort*)(W + NOFF_A1LO);
    ushort* A2h = (ushort*)(W + NOFF_A2HI);
    ushort* A2l = (ushort*)(W + NOFF_A2LO);
    ushort* A3h = (ushort*)(W + NOFF_A3HI);
    ushort* A3l = (ushort*)(W + NOFF_A3LO);
    ushort* A5h = (ushort*)(W + NOFF_A5HI);
    ushort* A5l = (ushort*)(W + NOFF_A5LO);
    ushort* A6h = (ushort*)(W + NOFF_A6HI);
    ushort* A6l = (ushort*)(W + NOFF_A6LO);
    ushort* A4h = (ushort*)(W + NOFF_A4HI);
    ushort* A4l = (ushort*)(W + NOFF_A4LO);
    ushort* KtH = (ushort*)(W + NOFF_KTH);
    uchar*  KtL = (uchar*)(W + NOFF_KTL);
    ushort* VbH = (ushort*)(W + NOFF_VBH);
    uchar*  VbL = (uchar*)(W + NOFF_VBL);

    hipMemsetAsync(d_ws, 0, 393216ull * 4ull, stream);
    detect_kernel<<<1, 64, 0, stream>>>(pp, flags);
    bias_cvt<<<16, 256, 0, stream>>>(d_in[2], d_in[4], d_in[7], d_in[8],
                                     d_in[11], d_in[12], d_in[14], flags,
                                     bqF, boF, b1c, b2c, boutF);
    bias_fold<<<16, 256, 0, stream>>>(d_in[5], flags, boF, b1c);
    weff_gemm<<<dim3(16, 64), 256, 0, stream>>>(d_in[5], d_in[3], flags, scratch);
    kv_gemm<<<dim3(32, 256), 256, 0, stream>>>(d_in[0], d_in[1], flags, bqF,
                                               (void*)KtH, (void*)VbH, KtL, VbL, 1);
    // weight conversions (A5 from scratch FIRST, then A1 overwrites scratch)
    wconv_kernel<<<2048, 256, 0, stream>>>(scratch, flags, -1, 1024, 0, 8192, A5h, A5l);
    wconv_kernel<<<2048, 256, 0, stream>>>(d_in[5], flags, 5, 2048, 0, 8192, A1h, A1l);
    wconv_kernel<<<2048, 256, 0, stream>>>(d_in[6], flags, 6, 1024, 0, 8192, A2h, A2l);
    wconv_kernel<<<2048, 256, 0, stream>>>(d_in[10], flags, 10, 1024, 0, 8192, A3h, A3l);
    wconv_kernel<<<2048, 256, 0, stream>>>(d_in[9], flags, 9, 1024, 0, 8192, A6h, A6l);
    wconv_kernel<<<512, 256, 0, stream>>>(d_in[1], flags, 1, 1024, 0, 2048, A4h, A4l);

    for (int s = 0; s < S_LEN; s++) {
      qhead_kernel<<<96, 512, 0, stream>>>(h2, h2h, h2l, A4h, A4l, d_in[13], flags,
                                           bqF, boutF, qv, out, s);
      mega_kernel<<<384, 512, 0, stream>>>(qv, KtH, KtL, VbH, VbL, h1h, h1l, h2h, h2l,
                                           A1h, A1l, A2h, A2l, A3h, A3l,
                                           b1c, b2c, crh, crl, g1p, g2p);
      lstm_fused<<<256, 256, 0, stream>>>(crh, crl, A5h, A5l, g1p, c1, h1, h1h, h1l);
      lstm_fused<<<256, 256, 0, stream>>>(h1h, h1l, A6h, A6l, g2p, c2, h2, h2h, h2l);
    }
    outhead_kernel<<<64, 256, 0, stream>>>(h2, d_in[13], flags, boutF, out, 255);
  } else if (ws_size >= FWS_NEED) {
    // ---------------- round-5 fast path (proven) ----------------
    float* h1    = W + OFF_H1;
    float* c1    = W + OFF_C1;
    float* h2    = W + OFF_H2;
    float* c2    = W + OFF_C2;
    float* qv    = W + FOFF_QV;
    float* cr    = W + FOFF_CR;
    float* g1p   = W + FOFF_G1P;
    float* g2p   = W + FOFF_G2P;
    float* P     = W + FOFF_P;
    float* b1c   = W + FOFF_B1C;
    float* b2c   = W + FOFF_B2C;
    float* bqF   = W + FOFF_BQ;
    float* boF   = W + FOFF_BO;
    float* boutF = W + FOFF_BOUT;
    int*   flags = (int*)(W + FOFF_FLAGS);
    float* Weff  = W + FOFF_WEFF;
    float* Kt    = W + FOFF_KT;
    float* Vb    = W + FOFF_VB;

    hipMemsetAsync(d_ws, 0, 4 * 65536 * sizeof(float), stream);
    detect_kernel<<<1, 64, 0, stream>>>(pp, flags);
    bias_cvt<<<16, 256, 0, stream>>>(d_in[2], d_in[4], d_in[7], d_in[8],
                                     d_in[11], d_in[12], d_in[14], flags,
                                     bqF, boF, b1c, b2c, boutF);
    bias_fold<<<16, 256, 0, stream>>>(d_in[5], flags, boF, b1c);
    weff_gemm<<<dim3(16, 64), 256, 0, stream>>>(d_in[5], d_in[3], flags, Weff);
    kv_gemm<<<dim3(32, 256), 256, 0, stream>>>(d_in[0], d_in[1], flags, bqF,
                                               (void*)Kt, (void*)Vb, nullptr, nullptr, 0);

    for (int s = 0; s < S_LEN; s++) {
      p1_fast<<<208, 256, 0, stream>>>(h1, h2, d_in[5], d_in[6], d_in[10],
                                       d_in[1], d_in[13], flags, b1c, b2c,
                                       bqF, boutF, g1p, g2p, qv, out, s);
      attn_kernel<<<256, 256, 0, stream>>>(qv, Kt, Vb, cr);
      lstm_gemm<<<256, 256, 0, stream>>>(cr, Weff, flags, -1, P);
      lstm_ew<<<256, 256, 0, stream>>>(g1p, P, c1, h1);
      lstm_gemm<<<256, 256, 0, stream>>>(h1, d_in[9], flags, 9, P);
      lstm_ew<<<256, 256, 0, stream>>>(g2p, P, c2, h2);
    }
    outhead_kernel<<<64, 256, 0, stream>>>(h2, d_in[13], flags, boutF, out, 255);
  } else if (ws_size >= WS_NEED) {
    // ---------------- round-4 slow path (proven) ----------------
    float* h1    = W + OFF_H1;
    float* c1    = W + OFF_C1;
    float* h2    = W + OFF_H2;
    float* c2    = W + OFF_C2;
    float* qvb   = W + OFF_Q;
    float* cr    = W + OFF_CR;
    float* cx    = W + OFF_CX;
    float* g1p   = W + OFF_G1;
    float* g2p   = W + OFF_G2;
    float* b1c   = W + OFF_B1C;
    float* b2c   = W + OFF_B2C;
    float* bqF   = W + OFF_BQ;
    float* boF   = W + OFF_BO;
    float* boutF = W + OFF_BOUT;
    int*   flags = (int*)(W + OFF_FLAGS);
    float* Kt    = W + OFF_KT;
    float* Vb    = W + OFF_VB;

    hipMemsetAsync(d_ws, 0, 4 * 65536 * sizeof(float), stream);
    detect_kernel<<<1, 64, 0, stream>>>(pp, flags);
    bias_cvt<<<16, 256, 0, stream>>>(d_in[2], d_in[4], d_in[7], d_in[8],
                                     d_in[11], d_in[12], d_in[14], flags,
                                     bqF, boF, b1c, b2c, boutF);
    kv_gemm<<<dim3(32, 256), 256, 0, stream>>>(d_in[0], d_in[1], flags, bqF,
                                               (void*)Kt, (void*)Vb, nullptr, nullptr, 0);

    for (int s = 0; s < S_LEN; s++) {
      p1_kernel<<<1344, 256, 0, stream>>>(h1, h2, d_in[5], d_in[6], d_in[10],
                                          d_in[1], d_in[13], flags, b1c, b2c,
                                          bqF, boutF, g1p, g2p, qvb, out, s);
      attn_kernel<<<256, 256, 0, stream>>>(qvb, Kt, Vb, cr);
      oproj_kernel<<<256, 256, 0, stream>>>(cr, d_in[3], flags, boF, cx);
      lstm_kernel<<<256, 256, 0, stream>>>(cx, d_in[5], flags, 5, 2048, 1024, g1p, c1, h1);
      lstm_kernel<<<256, 256, 0, stream>>>(h1, d_in[9], flags, 9, 1024, 0, g2p, c2, h2);
    }
    outhead_kernel<<<64, 256, 0, stream>>>(h2, d_in[13], flags, boutF, out, 255);
  }
}

// Round 10
// 32028.806 us; speedup vs baseline: 1.0821x; 1.0821x over previous
//
#include <hip/hip_runtime.h>
#include <hip/hip_bf16.h>
#include <hip/hip_fp16.h>

// StrokeRecoveryModel: S=256 seq steps, B=64, E=1024, H=4, D=256, V=5.
// Round 15: R14 (attn vectorized loads) was neutral-negative (34.66 vs
// 34.31ms) -> reverted to R13's scalar attn. This round rebalances the
// 4-launch chain: gate GEMMs move from mega into the qhead launch (legal:
// gates depend only on h1/h2, not on attention). New shape:
//   p1 (224 blk: 32 qgemm + 64 outhead + 64 g1p + 64 g2p)
//   mega (256 blk: attention only — exactly 1 block/CU, no tail)
//   lstm1 (256 blk), lstm2 (256 blk)
// All device bodies byte-identical to R13 (34.31ms, absmax 0.00390625).
// K/V fp16hi+e5m2lo; weights lossless bf16 hi/lo (3-mfma Markidis).
// R5/R4 fallback paths retained.

#define S_LEN 256

// ---------------- slow-path (round-4) layout: proven to fit ----------------
#define OFF_H1    0
#define OFF_C1    65536
#define OFF_H2    131072
#define OFF_C2    196608
#define OFF_Q     262144
#define OFF_CR    327680
#define OFF_CX    393216
#define OFF_G1    458752
#define OFF_G2    720896
#define OFF_B1C   983040
#define OFF_B2C   987136
#define OFF_BQ    991232
#define OFF_BO    994304
#define OFF_BOUT  995328
#define OFF_FLAGS 995336
#define OFF_KT    995360
#define OFF_VB    (995360 + 16777216)
#define WS_FLOATS (995360ull + 2ull * 16777216ull)
#define WS_NEED   (WS_FLOATS * 4ull)

// ---------------- round-5 fast-path layout ----------------
#define FOFF_QV    262144
#define FOFF_CR    327680
#define FOFF_G1P   393216
#define FOFF_G2P   655360
#define FOFF_P     917504
#define FOFF_B1C   1966080
#define FOFF_B2C   1970176
#define FOFF_BQ    1974272
#define FOFF_BO    1977344
#define FOFF_BOUT  1978368
#define FOFF_FLAGS 1978376
#define FOFF_WEFF  1978400
#define FOFF_KT    6172704
#define FOFF_VB    22949920
#define FWS_FLOATS 39727136ull
#define FWS_NEED   (FWS_FLOATS * 4ull)

// ---------------- round-11/15 MFMA-path layout (floats) ----------------
#define NOFF_H1    0
#define NOFF_C1    65536
#define NOFF_H2    131072
#define NOFF_C2    196608
#define NOFF_H1HI  262144
#define NOFF_H1LO  294912
#define NOFF_H2HI  327680
#define NOFF_H2LO  360448
#define NOFF_CRHI  393216
#define NOFF_CRLO  425984
#define NOFF_Q     458752
#define NOFF_G1P   524288
#define NOFF_G2P   786432
#define NOFF_B1C   1048576
#define NOFF_B2C   1052672
#define NOFF_BQ    1056768
#define NOFF_BO    1059840
#define NOFF_BOUT  1060864
#define NOFF_FLAGS 1060872
#define NOFF_A1HI  1060896
#define NOFF_A1LO  3158048
#define NOFF_A2HI  5255200
#define NOFF_A2LO  7352352
#define NOFF_A3HI  9449504
#define NOFF_A3LO  11546656
#define NOFF_A5HI  13643808
#define NOFF_A5LO  15740960
#define NOFF_A6HI  17838112
#define NOFF_A6LO  19935264
#define NOFF_A4HI  22032416
#define NOFF_A4LO  22556704
#define NOFF_KTH   23080992
#define NOFF_KTL   31469600
#define NOFF_VBH   35663904
#define NOFF_VBL   44052512
#define NWS_FLOATS 48246816ull
#define NWS_NEED   (NWS_FLOATS * 4ull)   // 192,987,264 B (< 226.5 MB proven)

typedef unsigned int uint;
typedef unsigned short ushort;
typedef unsigned char uchar;

typedef __attribute__((ext_vector_type(8))) short short8v;   // 8 bf16 = 4 VGPR
typedef __attribute__((ext_vector_type(4))) float f32x4;

__device__ __forceinline__ float sigm(float x) { return 1.f / (1.f + __expf(-x)); }
__device__ __forceinline__ float bfl(uint u) { return __uint_as_float(u << 16); }
__device__ __forceinline__ float bfh(uint u) { return __uint_as_float(u & 0xffff0000u); }

// round-to-nearest-even fp32 -> bf16 bits
__device__ __forceinline__ ushort f2bf(float x) {
  uint u = __float_as_uint(x);
  return (ushort)((u + 0x7fffu + ((u >> 16) & 1u)) >> 16);
}
__device__ __forceinline__ float bf2f(ushort u) { return __uint_as_float(((uint)u) << 16); }

// fp16 bit helpers (hi/lo split storage for K/V)
__device__ __forceinline__ ushort h_bits(__half h) {
  ushort u; __builtin_memcpy(&u, &h, 2); return u;
}
__device__ __forceinline__ float h2f_bits(ushort u) {
  __half h; __builtin_memcpy(&h, &u, 2); return __half2float(h);
}

__device__ __forceinline__ f32x4 mfma16(short8v a, short8v b, f32x4 c) {
  return __builtin_amdgcn_mfma_f32_16x16x32_bf16(a, b, c, 0, 0, 0);
}

// flag-branched loads (wave-uniform flag => ~free)
__device__ __forceinline__ float4 ld4f(const void* p, size_t i, int bf) {
  if (bf) {
    uint2 u = *(const uint2*)((const ushort*)p + i);
    return make_float4(bfl(u.x), bfh(u.x), bfl(u.y), bfh(u.y));
  }
  return *(const float4*)((const float*)p + i);
}
__device__ __forceinline__ float ld1f(const void* p, size_t i, int bf) {
  if (bf) return __uint_as_float(((uint)((const ushort*)p)[i]) << 16);
  return ((const float*)p)[i];
}

// ---------------------------------------------------------------------------
// Shared-memory union for the fused kernels
// ---------------------------------------------------------------------------
union SharedU {
  struct { float lq[256]; float latt[256]; float part[512]; float red[8]; } a;
  float sg[4][32][17];
  float red2[40];
};

// ---------------------------------------------------------------------------
// Device phase bodies (byte-identical to R13)
// ---------------------------------------------------------------------------
__device__ __forceinline__ void do_qgemm(
    const ushort* h2h, const ushort* h2l, const ushort* A4h, const ushort* A4l,
    const float* bqF, float* qv, int unit, int t) {
  int nb = unit & 15, mhalf = unit >> 4;
  int l = t & 63, w = t >> 6;
  int nt = w & 3, mq = w >> 2;
  int col = l & 15, klane = l >> 4;
  int ntg = (nb << 2) + nt;
  const short8v* Xh = (const short8v*)h2h;
  const short8v* Xl = (const short8v*)h2l;
  const short8v* Bh = (const short8v*)A4h;
  const short8v* Bl = (const short8v*)A4l;
  size_t wbase = (size_t)(ntg << 5) * 64 + l;
  int m0 = (mhalf << 5) + (mq << 4) + col;
  f32x4 acc = {0.f, 0.f, 0.f, 0.f};
#pragma unroll 4
  for (int kt = 0; kt < 32; ++kt) {
    short8v bh = Bh[wbase + (kt << 6)];
    short8v bl = Bl[wbase + (kt << 6)];
    int ia = (m0 << 7) + (kt << 2) + klane;
    short8v a_h = Xh[ia], a_l = Xl[ia];
    acc = mfma16(a_h, bh, acc);
    acc = mfma16(a_l, bh, acc);
    acc = mfma16(a_h, bl, acc);
  }
  int n = (ntg << 4) + col;
  float bias = bqF[n];
#pragma unroll
  for (int r = 0; r < 4; ++r) {
    int m = (mhalf << 5) + (mq << 4) + (klane << 2) + r;
    qv[(m << 10) + n] = acc[r] + bias;
  }
}

// 512-thread out head; writes out[srow*64+b].
__device__ __forceinline__ void do_outhead(
    const float* h2, const void* wout, const int* flags, const float* boutF,
    float* out, int b, int srow, int t, float* red2) {
  int f13 = flags[13];
  float p[5] = {0.f, 0.f, 0.f, 0.f, 0.f};
  for (int e = t; e < 1024; e += 512) {
    float hv = h2[(b << 10) + e];
#pragma unroll
    for (int v = 0; v < 5; v++) p[v] += hv * ld1f(wout, (size_t)(v << 10) + e, f13);
  }
#pragma unroll
  for (int v = 0; v < 5; v++)
#pragma unroll
    for (int o = 32; o >= 1; o >>= 1) p[v] += __shfl_xor(p[v], o, 64);
  int l = t & 63, w = t >> 6;
  if (l == 0) {
#pragma unroll
    for (int v = 0; v < 5; v++) red2[w * 5 + v] = p[v];
  }
  __syncthreads();
  if (t < 5) {
    float a = boutF[t];
    for (int w2 = 0; w2 < 8; w2++) a += red2[w2 * 5 + t];
    if (t >= 2) a = sigm(a);
    out[(srow * 64 + b) * 5 + t] = a;
  }
}

// split K/V attention: k = fp16(hi) + fp16(lo<<8), fp32 accumulate. (R13)
__device__ __forceinline__ void do_attn(
    const float* qv,
    const ushort* KtH, const uchar* KtL, const ushort* VbH, const uchar* VbL,
    ushort* crh, ushort* crl, int p, int t, SharedU& su) {
  float* lq = su.a.lq;
  float* latt = su.a.latt;
  float* part = su.a.part;
  float* red = su.a.red;
  int b = p >> 2, h = p & 3;
  if (t < 256) lq[t] = qv[(b << 10) + (h << 8) + t];
  __syncthreads();
  int s2 = t & 255, dh = t >> 8;
  const ushort* KpH = KtH + (((size_t)p) << 16) + (dh << 15);
  const uchar*  KpL = KtL + (((size_t)p) << 16) + (dh << 15);
  float sc = 0.f;
#pragma unroll 8
  for (int d = 0; d < 128; ++d) {
    int idx = (d << 8) + s2;
    float kv = h2f_bits(KpH[idx]) + h2f_bits((ushort)((uint)KpL[idx] << 8));
    sc += lq[(dh << 7) + d] * kv;
  }
  part[t] = sc;
  __syncthreads();
  sc = (part[s2] + part[s2 + 256]) * 0.0625f;
  float mx = sc;
#pragma unroll
  for (int o = 32; o >= 1; o >>= 1) mx = fmaxf(mx, __shfl_xor(mx, o, 64));
  if ((t & 63) == 0) red[t >> 6] = mx;
  __syncthreads();
  mx = red[0];
#pragma unroll
  for (int i = 1; i < 8; ++i) mx = fmaxf(mx, red[i]);
  float e = __expf(sc - mx);
  float ss = e;
#pragma unroll
  for (int o = 32; o >= 1; o >>= 1) ss += __shfl_xor(ss, o, 64);
  __syncthreads();
  if ((t & 63) == 0) red[t >> 6] = ss;
  __syncthreads();
  ss = (red[0] + red[1] + red[2] + red[3] + red[4] + red[5] + red[6] + red[7]) * 0.5f;
  if (t < 256) latt[t] = e / ss;
  __syncthreads();
  int d = t & 255, sh = t >> 8;
  const ushort* VpH = VbH + (((size_t)p) << 16) + (sh << 15);
  const uchar*  VpL = VbL + (((size_t)p) << 16) + (sh << 15);
  float cv = 0.f;
#pragma unroll 8
  for (int s3 = 0; s3 < 128; ++s3) {
    int idx = (s3 << 8) + d;
    float vv = h2f_bits(VpH[idx]) + h2f_bits((ushort)((uint)VpL[idx] << 8));
    cv += latt[(sh << 7) + s3] * vv;
  }
  part[t] = cv;
  __syncthreads();
  if (t < 256) {
    float v = part[t] + part[t + 256];
    int idx = (b << 10) + (h << 8) + t;
    ushort hu = f2bf(v);
    crh[idx] = hu;
    crl[idx] = f2bf(v - bf2f(hu));
  }
}

__device__ __forceinline__ void gg_pass(
    const ushort* xh, const ushort* xl, const ushort* Ah, const ushort* Al,
    size_t wbase, int m0, f32x4& acc0, f32x4& acc1) {
  const short8v* Xh = (const short8v*)xh;
  const short8v* Xl = (const short8v*)xl;
  const short8v* Bh = (const short8v*)Ah;
  const short8v* Bl = (const short8v*)Al;
  int klane = ((int)(wbase & 63)) >> 4;
#pragma unroll 4
  for (int kt = 0; kt < 32; ++kt) {
    short8v bh = Bh[wbase + (kt << 6)];
    short8v bl = Bl[wbase + (kt << 6)];
    int iaa = (m0 << 7) + (kt << 2) + klane;
    short8v ah0 = Xh[iaa], al0 = Xl[iaa];
    short8v ah1 = Xh[iaa + 2048], al1 = Xl[iaa + 2048];
    acc0 = mfma16(ah0, bh, acc0); acc0 = mfma16(al0, bh, acc0); acc0 = mfma16(ah0, bl, acc0);
    acc1 = mfma16(ah1, bh, acc1); acc1 = mfma16(al1, bh, acc1); acc1 = mfma16(ah1, bl, acc1);
  }
}

__device__ __forceinline__ void do_gate(
    const ushort* h2h, const ushort* h2l, const ushort* h1h, const ushort* h1l,
    const ushort* W1h, const ushort* W1l, const ushort* W2h, const ushort* W2l,
    const float* bias, float* gout, int two_pass, int b2, int t) {
  int l = t & 63, w = t >> 6;
  int nt = w & 3, mh = w >> 2;
  int col = l & 15;
  f32x4 acc0 = {0.f, 0.f, 0.f, 0.f}, acc1 = {0.f, 0.f, 0.f, 0.f};
  int ntg = (b2 << 2) + nt;
  size_t wbase = (size_t)(ntg << 5) * 64 + l;
  int m0 = (mh << 5) + col;
  gg_pass(h2h, h2l, W1h, W1l, wbase, m0, acc0, acc1);
  if (two_pass) gg_pass(h1h, h1l, W2h, W2l, wbase, m0, acc0, acc1);
  int n = (ntg << 4) + col;
  float bv = bias[n];
  int klane = l >> 4;
#pragma unroll
  for (int r = 0; r < 4; ++r) {
    int mrow = (klane << 2) + r;
    gout[(size_t)((mh << 5) + mrow) * 4096 + n] = acc0[r] + bv;
    gout[(size_t)((mh << 5) + 16 + mrow) * 4096 + n] = acc1[r] + bv;
  }
}

// 256-thread lstm block — one (j-tile, m-quarter); 4 waves = 4 gates.
__device__ __forceinline__ void do_lstm256(
    const ushort* xh, const ushort* xl, const ushort* Wh, const ushort* Wl,
    const float* gpart, float* cbuf, float* hbuf, ushort* hhi, ushort* hlo,
    int unit, int t, float sg[4][16][17]) {
  int jt = unit & 63, mq4 = unit >> 6;       // 0..63, 0..3
  int l = t & 63, g = t >> 6;                // 4 waves, one gate each
  int col = l & 15, klane = l >> 4;
  int ntg = (g << 6) + jt;
  const short8v* Xh = (const short8v*)xh;
  const short8v* Xl = (const short8v*)xl;
  const short8v* Bh = (const short8v*)Wh;
  const short8v* Bl = (const short8v*)Wl;
  size_t wbase = (size_t)(ntg << 5) * 64 + l;
  int m0 = (mq4 << 4) + col;
  f32x4 acc = {0.f, 0.f, 0.f, 0.f};
#pragma unroll 4
  for (int kt = 0; kt < 32; ++kt) {
    short8v bh = Bh[wbase + (kt << 6)];
    short8v bl = Bl[wbase + (kt << 6)];
    int ia = (m0 << 7) + (kt << 2) + klane;
    short8v a_h = Xh[ia], a_l = Xl[ia];
    acc = mfma16(a_h, bh, acc);
    acc = mfma16(a_l, bh, acc);
    acc = mfma16(a_h, bl, acc);
  }
#pragma unroll
  for (int r = 0; r < 4; ++r)
    sg[g][(klane << 2) + r][col] = acc[r];
  __syncthreads();
  int ml = t >> 4, j = t & 15;               // 16 m x 16 j = 256 threads
  int m = (mq4 << 4) + ml;
  int jj = (jt << 4) + j;
  size_t gb = (size_t)m * 4096 + jj;
  float gi = sg[0][ml][j] + gpart[gb];
  float gf = sg[1][ml][j] + gpart[gb + 1024];
  float gg = sg[2][ml][j] + gpart[gb + 2048];
  float go = sg[3][ml][j] + gpart[gb + 3072];
  gi = sigm(gi); gf = sigm(gf); gg = tanhf(gg); go = sigm(go);
  int hb = (m << 10) + jj;
  float c = gf * cbuf[hb] + gi * gg;
  cbuf[hb] = c;
  float hval = go * tanhf(c);
  hbuf[hb] = hval;
  ushort hu = f2bf(hval);
  hhi[hb] = hu;
  hlo[hb] = f2bf(hval - bf2f(hu));
}

// ---------------------------------------------------------------------------
// dtype detector + bias canonicalization (shared by all paths)
// ---------------------------------------------------------------------------
struct Ptrs { const void* p[15]; int n[15]; };

__global__ __launch_bounds__(64) void detect_kernel(Ptrs pp, int* flags) {
  int lane = threadIdx.x;
  for (int i = 0; i < 15; i++) {
    int nw = pp.n[i] / 2;
    if (nw > 64) nw = 64;
    int pass = 0;
    if (lane < nw) {
      uint w = ((const uint*)pp.p[i])[lane];
      uint ex = (w >> 7) & 0xFFu;
      pass = (ex >= 96u && ex <= 134u) ? 1 : 0;
    }
    unsigned long long bal = __ballot(pass);
    int cnt = __popcll(bal);
    if (lane == 0) flags[i] = (cnt * 4 >= nw * 3) ? 1 : 0;
  }
}

__global__ __launch_bounds__(256) void bias_cvt(
    const void* bqkv, const void* bo, const void* bih1, const void* bhh1,
    const void* bih2, const void* bhh2, const void* bout, const int* __restrict__ flags,
    float* bqF, float* boF, float* b1c, float* b2c, float* boutF) {
  int j = blockIdx.x * 256 + threadIdx.x;
  if (j < 3072) bqF[j] = ld1f(bqkv, j, flags[2]);
  if (j < 1024) boF[j] = ld1f(bo, j, flags[4]);
  if (j < 4096) {
    b1c[j] = ld1f(bih1, j, flags[7]) + ld1f(bhh1, j, flags[8]);
    b2c[j] = ld1f(bih2, j, flags[11]) + ld1f(bhh2, j, flags[12]);
  }
  if (j < 5) boutF[j] = ld1f(bout, j, flags[14]);
}

// b1c[j] += sum_m wih1[j,1024+m] * b_o[m]   (o-proj bias fold)
__global__ __launch_bounds__(256) void bias_fold(
    const void* __restrict__ wih1, const int* __restrict__ flags,
    const float* __restrict__ boF, float* __restrict__ b1c) {
  __shared__ float lbo[1024];
  int t = threadIdx.x;
  ((float4*)lbo)[t] = ((const float4*)boF)[t];
  __syncthreads();
  int f5 = flags[5];
  int j = blockIdx.x * 256 + t;
  size_t r = (size_t)j * 2048 + 1024;
  float acc = 0.f;
#pragma unroll 4
  for (int i = 0; i < 256; i++) {
    float4 w4 = ld4f(wih1, r + 4 * i, f5);
    float4 x4 = ((float4*)lbo)[i];
    acc += w4.x * x4.x + w4.y * x4.y + w4.z * x4.z + w4.w * x4.w;
  }
  b1c[j] += acc;
}

// ---------------------------------------------------------------------------
// KV GEMM (one-time, fp32 math): C[16384,2048] = cnn @ w_qkv[1024:3072]^T
// (+bias). mode=1: scatter fp16-hi + e5m2-lo; mode=0: fp32 (fallbacks).
// ---------------------------------------------------------------------------
__global__ __launch_bounds__(256) void kv_gemm(
    const void* __restrict__ A, const void* __restrict__ Wq,
    const int* __restrict__ flags, const float* __restrict__ bqF,
    void* __restrict__ KtvH, void* __restrict__ VbvH,
    uchar* __restrict__ KtL, uchar* __restrict__ VbL, int mode) {
  __shared__ float sA[16][65];
  __shared__ float sB[16][65];
  int f0 = flags[0], f1 = flags[1];
  int m0 = blockIdx.y << 6;
  int n0 = blockIdx.x << 6;
  int t = threadIdx.x;
  int lm = t >> 2, lk = (t & 3) << 2;
  int tx = t & 15, ty = t >> 4;
  float acc[4][4] = {};
  for (int k0 = 0; k0 < 1024; k0 += 16) {
    float4 a4 = ld4f(A, (size_t)(m0 + lm) * 1024 + k0 + lk, f0);
    float4 b4 = ld4f(Wq, (size_t)(1024 + n0 + lm) * 1024 + k0 + lk, f1);
    __syncthreads();
    sA[lk + 0][lm] = a4.x; sA[lk + 1][lm] = a4.y; sA[lk + 2][lm] = a4.z; sA[lk + 3][lm] = a4.w;
    sB[lk + 0][lm] = b4.x; sB[lk + 1][lm] = b4.y; sB[lk + 2][lm] = b4.z; sB[lk + 3][lm] = b4.w;
    __syncthreads();
#pragma unroll
    for (int k = 0; k < 16; k++) {
      float av[4], bv[4];
#pragma unroll
      for (int i = 0; i < 4; i++) av[i] = sA[k][ty * 4 + i];
#pragma unroll
      for (int j = 0; j < 4; j++) bv[j] = sB[k][tx * 4 + j];
#pragma unroll
      for (int i = 0; i < 4; i++)
#pragma unroll
        for (int j = 0; j < 4; j++) acc[i][j] += av[i] * bv[j];
    }
  }
#pragma unroll
  for (int i = 0; i < 4; i++) {
    int m = m0 + ty * 4 + i;
    int s = m >> 6, b = m & 63;
#pragma unroll
    for (int j = 0; j < 4; j++) {
      int n = n0 + tx * 4 + j;
      float v = acc[i][j];
      if (n < 1024) {
        int h = n >> 8, d = n & 255;
        v += bqF[1024 + n];
        size_t idx = ((size_t)(((b << 2) | h) << 8 | d) << 8) | s;
        if (mode) {
          __half hh = __float2half(v);
          float rr = v - __half2float(hh);
          ushort rb = h_bits(__float2half(rr));
          ((ushort*)KtvH)[idx] = h_bits(hh);
          KtL[idx] = (uchar)(((uint)rb + 0x80u) >> 8);
        } else {
          ((float*)KtvH)[idx] = v;
        }
      } else {
        int nn = n - 1024;
        int h = nn >> 8, d = nn & 255;
        v += bqF[2048 + nn];
        size_t idx = ((size_t)(((b << 2) | h) << 8 | s) << 8) | d;
        if (mode) {
          __half hh = __float2half(v);
          float rr = v - __half2float(hh);
          ushort rb = h_bits(__float2half(rr));
          ((ushort*)VbvH)[idx] = h_bits(hh);
          VbL[idx] = (uchar)(((uint)rb + 0x80u) >> 8);
        } else {
          ((float*)VbvH)[idx] = v;
        }
      }
    }
  }
}

// ---------------------------------------------------------------------------
// Weff[4096,1024] = wih1[:,1024:] @ w_o   (fp32 out, one-time)
// ---------------------------------------------------------------------------
__global__ __launch_bounds__(256) void weff_gemm(
    const void* __restrict__ wih1, const void* __restrict__ wo,
    const int* __restrict__ flags, float* __restrict__ Weff) {
  __shared__ float sA[16][65];
  __shared__ float sB[16][65];
  int f5 = flags[5], f3 = flags[3];
  int m0 = blockIdx.y << 6;
  int n0 = blockIdx.x << 6;
  int t = threadIdx.x;
  int lm = t >> 2, lk = (t & 3) << 2;
  int kk = t >> 4, nn2 = (t & 15) << 2;
  int tx = t & 15, ty = t >> 4;
  float acc[4][4] = {};
  for (int k0 = 0; k0 < 1024; k0 += 16) {
    float4 a4 = ld4f(wih1, (size_t)(m0 + lm) * 2048 + 1024 + k0 + lk, f5);
    float4 b4 = ld4f(wo, (size_t)(k0 + kk) * 1024 + n0 + nn2, f3);
    __syncthreads();
    sA[lk + 0][lm] = a4.x; sA[lk + 1][lm] = a4.y; sA[lk + 2][lm] = a4.z; sA[lk + 3][lm] = a4.w;
    sB[kk][nn2 + 0] = b4.x; sB[kk][nn2 + 1] = b4.y; sB[kk][nn2 + 2] = b4.z; sB[kk][nn2 + 3] = b4.w;
    __syncthreads();
#pragma unroll
    for (int k = 0; k < 16; k++) {
      float av[4], bv[4];
#pragma unroll
      for (int i = 0; i < 4; i++) av[i] = sA[k][ty * 4 + i];
#pragma unroll
      for (int j = 0; j < 4; j++) bv[j] = sB[k][tx * 4 + j];
#pragma unroll
      for (int i = 0; i < 4; i++)
#pragma unroll
        for (int j = 0; j < 4; j++) acc[i][j] += av[i] * bv[j];
    }
  }
#pragma unroll
  for (int i = 0; i < 4; i++)
#pragma unroll
    for (int j = 0; j < 4; j++)
      Weff[(size_t)(m0 + ty * 4 + i) * 1024 + n0 + tx * 4 + j] = acc[i][j];
}

// ---------------------------------------------------------------------------
// weight hi/lo split + MFMA-fragment shuffle
// ---------------------------------------------------------------------------
__global__ __launch_bounds__(256) void wconv_kernel(
    const void* __restrict__ src, const int* __restrict__ flags, int fidx,
    int rs, int co, int ntiles, ushort* __restrict__ dh, ushort* __restrict__ dl) {
  int gid = blockIdx.x * 256 + threadIdx.x;
  int tile = gid >> 6, l = gid & 63;
  if (tile >= ntiles) return;
  int kt = tile & 31, nt = tile >> 5;
  int n = (nt << 4) + (l & 15);
  int k = (kt << 5) + ((l >> 4) << 3);
  int bf = (fidx >= 0) ? flags[fidx] : 0;
  size_t base = (size_t)n * rs + co + k;
  float v[8];
  if (!bf) {
    float4 x0 = *(const float4*)((const float*)src + base);
    float4 x1 = *(const float4*)((const float*)src + base + 4);
    v[0] = x0.x; v[1] = x0.y; v[2] = x0.z; v[3] = x0.w;
    v[4] = x1.x; v[5] = x1.y; v[6] = x1.z; v[7] = x1.w;
  } else {
#pragma unroll
    for (int j = 0; j < 8; ++j) v[j] = ld1f(src, base + j, 1);
  }
  short8v hv, lv;
#pragma unroll
  for (int j = 0; j < 8; ++j) {
    ushort hu = f2bf(v[j]);
    hv[j] = (short)hu;
    lv[j] = (short)f2bf(v[j] - bf2f(hu));
  }
  size_t o = ((size_t)tile << 6) + l;
  ((short8v*)dh)[o] = hv;
  ((short8v*)dl)[o] = lv;
}

// ---------------------------------------------------------------------------
// Fast-path per-step kernels (R15: rebalanced 4-launch chain)
// ---------------------------------------------------------------------------
// p1: blocks 0..31 q-gemm, 32..95 outhead(s-1), 96..159 g1p, 160..223 g2p.
__global__ __launch_bounds__(512) void p1_fused(
    const float* __restrict__ h2, const ushort* __restrict__ h2h, const ushort* __restrict__ h2l,
    const ushort* __restrict__ h1h, const ushort* __restrict__ h1l,
    const ushort* __restrict__ A4h, const ushort* __restrict__ A4l,
    const ushort* __restrict__ A1h, const ushort* __restrict__ A1l,
    const ushort* __restrict__ A2h, const ushort* __restrict__ A2l,
    const ushort* __restrict__ A3h, const ushort* __restrict__ A3l,
    const void* __restrict__ wout, const int* __restrict__ flags,
    const float* __restrict__ bqF, const float* __restrict__ boutF,
    const float* __restrict__ b1c, const float* __restrict__ b2c,
    float* __restrict__ qv, float* __restrict__ out,
    float* __restrict__ g1p, float* __restrict__ g2p, int s) {
  __shared__ SharedU su;
  int bi = blockIdx.x, t = threadIdx.x;
  if (bi < 32) {
    do_qgemm(h2h, h2l, A4h, A4l, bqF, qv, bi, t);
  } else if (bi < 96) {
    if (s == 0) return;
    do_outhead(h2, wout, flags, boutF, out, bi - 32, s - 1, t, su.red2);
  } else if (bi < 160) {
    do_gate(h2h, h2l, h1h, h1l, A1h, A1l, A2h, A2l, b1c, g1p, 1, bi - 96, t);
  } else {
    do_gate(h2h, h2l, h1h, h1l, A3h, A3l, A3h, A3l, b2c, g2p, 0, bi - 160, t);
  }
}

// mega: 256 attention blocks exactly (1 block/CU).
__global__ __launch_bounds__(512) void mega_kernel(
    const float* __restrict__ qv,
    const ushort* __restrict__ KtH, const uchar* __restrict__ KtL,
    const ushort* __restrict__ VbH, const uchar* __restrict__ VbL,
    ushort* __restrict__ crh, ushort* __restrict__ crl) {
  __shared__ SharedU su;
  do_attn(qv, KtH, KtL, VbH, VbL, crh, crl, blockIdx.x, threadIdx.x, su);
}

// 256 blocks x 256 threads — full-chip coverage.
__global__ __launch_bounds__(256) void lstm_fused(
    const ushort* __restrict__ xh, const ushort* __restrict__ xl,
    const ushort* __restrict__ Wh, const ushort* __restrict__ Wl,
    const float* __restrict__ gpart, float* __restrict__ cbuf,
    float* __restrict__ hbuf, ushort* __restrict__ hhi, ushort* __restrict__ hlo) {
  __shared__ float sg[4][16][17];
  do_lstm256(xh, xl, Wh, Wl, gpart, cbuf, hbuf, hhi, hlo, blockIdx.x, threadIdx.x, sg);
}

// final output head (256-thr variant, used after loops)
__global__ __launch_bounds__(256) void outhead_kernel(
    const float* __restrict__ h2, const void* __restrict__ wout,
    const int* __restrict__ flags, const float* __restrict__ boutF,
    float* __restrict__ out, int row) {
  __shared__ float smem[1280];
  int b = blockIdx.x, t = threadIdx.x;
  int f13 = flags[13];
  float p[5] = {0.f, 0.f, 0.f, 0.f, 0.f};
#pragma unroll
  for (int k2 = 0; k2 < 4; k2++) {
    float hv = h2[(b << 10) + t + (k2 << 8)];
#pragma unroll
    for (int v = 0; v < 5; v++)
      p[v] += hv * ld1f(wout, (size_t)(v << 10) + t + (k2 << 8), f13);
  }
#pragma unroll
  for (int v = 0; v < 5; v++) smem[v * 256 + t] = p[v];
  __syncthreads();
  if (t < 5) {
    float acc = boutF[t];
    for (int i = 0; i < 256; i++) acc += smem[t * 256 + i];
    if (t >= 2) acc = sigm(acc);
    out[(row * 64 + b) * 5 + t] = acc;
  }
}

// ========================= SLOW PATHS (round-4/5, proven) ==================
__global__ __launch_bounds__(256) void p1_fast(
    const float* __restrict__ h1, const float* __restrict__ h2,
    const void* __restrict__ wih1, const void* __restrict__ whh1,
    const void* __restrict__ whh2, const void* __restrict__ wqkv,
    const void* __restrict__ wout, const int* __restrict__ flags,
    const float* __restrict__ b1c, const float* __restrict__ b2c,
    const float* __restrict__ bqF, const float* __restrict__ boutF,
    float* __restrict__ g1p, float* __restrict__ g2p,
    float* __restrict__ qv, float* __restrict__ out, int s) {
  __shared__ __align__(16) float sX[32][68];
  __shared__ __align__(16) float sW[32][68];
  int bi = blockIdx.x, t = threadIdx.x;

  if (bi >= 144) {
    if (s == 0) return;
    float* smem = &sX[0][0];
    int f13 = flags[13];
    int b = bi - 144;
    float p[5] = {0.f, 0.f, 0.f, 0.f, 0.f};
#pragma unroll
    for (int k2 = 0; k2 < 4; k2++) {
      float hv = h2[(b << 10) + t + (k2 << 8)];
#pragma unroll
      for (int v = 0; v < 5; v++)
        p[v] += hv * ld1f(wout, (size_t)(v << 10) + t + (k2 << 8), f13);
    }
#pragma unroll
    for (int v = 0; v < 5; v++) smem[v * 256 + t] = p[v];
    __syncthreads();
    if (t < 5) {
      float acc = boutF[t];
      for (int i = 0; i < 256; i++) acc += smem[t * 256 + i];
      if (t >= 2) acc = sigm(acc);
      out[((s - 1) * 64 + b) * 5 + t] = acc;
    }
    return;
  }

  int lm = t >> 2, lk8 = (t & 3) << 3;
  int tx = t & 15, ty = t >> 4;
  float acc[4][4] = {};

  int kind = (bi < 64) ? 0 : (bi < 128) ? 1 : 2;
  int n0 = (kind == 0) ? (bi << 6) : (kind == 1) ? ((bi - 64) << 6) : ((bi - 128) << 6);
  int Ktot = (kind == 0) ? 2048 : 1024;

  for (int k0 = 0; k0 < Ktot; k0 += 32) {
    const float* xs;
    const void* Wm;
    size_t wstride;
    int koff, bf;
    if (kind == 0) {
      if (k0 < 1024) { xs = h2; Wm = wih1; wstride = 2048; koff = k0; bf = flags[5]; }
      else           { xs = h1; Wm = whh1; wstride = 1024; koff = k0 - 1024; bf = flags[6]; }
    } else if (kind == 1) { xs = h2; Wm = whh2; wstride = 1024; koff = k0; bf = flags[10]; }
    else                  { xs = h2; Wm = wqkv; wstride = 1024; koff = k0; bf = flags[1]; }

    float4 xa = *(const float4*)(xs + (lm << 10) + koff + lk8);
    float4 xb = *(const float4*)(xs + (lm << 10) + koff + lk8 + 4);
    float4 wa = ld4f(Wm, (size_t)(n0 + lm) * wstride + koff + lk8, bf);
    float4 wb = ld4f(Wm, (size_t)(n0 + lm) * wstride + koff + lk8 + 4, bf);
    __syncthreads();
    sX[lk8 + 0][lm] = xa.x; sX[lk8 + 1][lm] = xa.y; sX[lk8 + 2][lm] = xa.z; sX[lk8 + 3][lm] = xa.w;
    sX[lk8 + 4][lm] = xb.x; sX[lk8 + 5][lm] = xb.y; sX[lk8 + 6][lm] = xb.z; sX[lk8 + 7][lm] = xb.w;
    sW[lk8 + 0][lm] = wa.x; sW[lk8 + 1][lm] = wa.y; sW[lk8 + 2][lm] = wa.z; sW[lk8 + 3][lm] = wa.w;
    sW[lk8 + 4][lm] = wb.x; sW[lk8 + 5][lm] = wb.y; sW[lk8 + 6][lm] = wb.z; sW[lk8 + 7][lm] = wb.w;
    __syncthreads();
#pragma unroll
    for (int k = 0; k < 32; k++) {
      float4 av = *(const float4*)&sX[k][ty << 2];
      float4 bv = *(const float4*)&sW[k][tx << 2];
      acc[0][0] += av.x * bv.x; acc[0][1] += av.x * bv.y; acc[0][2] += av.x * bv.z; acc[0][3] += av.x * bv.w;
      acc[1][0] += av.y * bv.x; acc[1][1] += av.y * bv.y; acc[1][2] += av.y * bv.z; acc[1][3] += av.y * bv.w;
      acc[2][0] += av.z * bv.x; acc[2][1] += av.z * bv.y; acc[2][2] += av.z * bv.z; acc[2][3] += av.z * bv.w;
      acc[3][0] += av.w * bv.x; acc[3][1] += av.w * bv.y; acc[3][2] += av.w * bv.z; acc[3][3] += av.w * bv.w;
    }
  }

  int col = n0 + (tx << 2);
  if (kind == 0) {
    float4 bias = *(const float4*)(b1c + col);
#pragma unroll
    for (int i = 0; i < 4; i++) {
      int b = (ty << 2) + i;
      *(float4*)(g1p + (b << 12) + col) =
          make_float4(acc[i][0] + bias.x, acc[i][1] + bias.y, acc[i][2] + bias.z, acc[i][3] + bias.w);
    }
  } else if (kind == 1) {
    float4 bias = *(const float4*)(b2c + col);
#pragma unroll
    for (int i = 0; i < 4; i++) {
      int b = (ty << 2) + i;
      *(float4*)(g2p + (b << 12) + col) =
          make_float4(acc[i][0] + bias.x, acc[i][1] + bias.y, acc[i][2] + bias.z, acc[i][3] + bias.w);
    }
  } else {
    float4 bias = *(const float4*)(bqF + col);
#pragma unroll
    for (int i = 0; i < 4; i++) {
      int b = (ty << 2) + i;
      *(float4*)(qv + (b << 10) + col) =
          make_float4(acc[i][0] + bias.x, acc[i][1] + bias.y, acc[i][2] + bias.z, acc[i][3] + bias.w);
    }
  }
}

__global__ __launch_bounds__(256) void lstm_gemm(
    const float* __restrict__ x, const void* __restrict__ Wm,
    const int* __restrict__ flags, int fidx, float* __restrict__ P) {
  __shared__ __align__(16) float sX[32][68];
  __shared__ __align__(16) float sW[32][68];
  int bi = blockIdx.x, t = threadIdx.x;
  int ks = bi >> 6;
  int n0 = (bi & 63) << 6;
  int kbase = ks << 8;
  int bf = (fidx >= 0) ? flags[fidx] : 0;
  int lm = t >> 2, lk8 = (t & 3) << 3;
  int tx = t & 15, ty = t >> 4;
  float acc[4][4] = {};
  for (int kc = 0; kc < 256; kc += 32) {
    int koff = kbase + kc;
    float4 xa = *(const float4*)(x + (lm << 10) + koff + lk8);
    float4 xb = *(const float4*)(x + (lm << 10) + koff + lk8 + 4);
    float4 wa = ld4f(Wm, (size_t)(n0 + lm) * 1024 + koff + lk8, bf);
    float4 wb = ld4f(Wm, (size_t)(n0 + lm) * 1024 + koff + lk8 + 4, bf);
    __syncthreads();
    sX[lk8 + 0][lm] = xa.x; sX[lk8 + 1][lm] = xa.y; sX[lk8 + 2][lm] = xa.z; sX[lk8 + 3][lm] = xa.w;
    sX[lk8 + 4][lm] = xb.x; sX[lk8 + 5][lm] = xb.y; sX[lk8 + 6][lm] = xb.z; sX[lk8 + 7][lm] = xb.w;
    sW[lk8 + 0][lm] = wa.x; sW[lk8 + 1][lm] = wa.y; sW[lk8 + 2][lm] = wa.z; sW[lk8 + 3][lm] = wa.w;
    sW[lk8 + 4][lm] = wb.x; sW[lk8 + 5][lm] = wb.y; sW[lk8 + 6][lm] = wb.z; sW[lk8 + 7][lm] = wb.w;
    __syncthreads();
#pragma unroll
    for (int k = 0; k < 32; k++) {
      float4 av = *(const float4*)&sX[k][ty << 2];
      float4 bv = *(const float4*)&sW[k][tx << 2];
      acc[0][0] += av.x * bv.x; acc[0][1] += av.x * bv.y; acc[0][2] += av.x * bv.z; acc[0][3] += av.x * bv.w;
      acc[1][0] += av.y * bv.x; acc[1][1] += av.y * bv.y; acc[1][2] += av.y * bv.z; acc[1][3] += av.y * bv.w;
      acc[2][0] += av.z * bv.x; acc[2][1] += av.z * bv.y; acc[2][2] += av.z * bv.z; acc[2][3] += av.z * bv.w;
      acc[3][0] += av.w * bv.x; acc[3][1] += av.w * bv.y; acc[3][2] += av.w * bv.z; acc[3][3] += av.w * bv.w;
    }
  }
  int col = n0 + (tx << 2);
  float* Pk = P + ((size_t)ks << 18);
#pragma unroll
  for (int i = 0; i < 4; i++) {
    int b = (ty << 2) + i;
    *(float4*)(Pk + (b << 12) + col) = make_float4(acc[i][0], acc[i][1], acc[i][2], acc[i][3]);
  }
}

__global__ __launch_bounds__(256) void lstm_ew(
    const float* __restrict__ gp, const float* __restrict__ P,
    float* __restrict__ cbuf, float* __restrict__ hbuf) {
  int b = blockIdx.x >> 2;
  int j = ((blockIdx.x & 3) << 8) + threadIdx.x;
  int base = (b << 12) + j;
  float g[4];
#pragma unroll
  for (int gi = 0; gi < 4; gi++) {
    int idx = base + (gi << 10);
    g[gi] = gp[idx] + P[idx] + P[idx + (1 << 18)] + P[idx + (2 << 18)] + P[idx + (3 << 18)];
  }
  float gi_ = sigm(g[0]);
  float gf_ = sigm(g[1]);
  float gg_ = tanhf(g[2]);
  float go_ = sigm(g[3]);
  float c = gf_ * cbuf[(b << 10) + j] + gi_ * gg_;
  cbuf[(b << 10) + j] = c;
  hbuf[(b << 10) + j] = go_ * tanhf(c);
}

__global__ __launch_bounds__(256) void attn_kernel(
    const float* __restrict__ qbuf, const float* __restrict__ Kt,
    const float* __restrict__ Vb, float* __restrict__ cr) {
  __shared__ float lq[256];
  __shared__ float latt[256];
  __shared__ float red[8];
  int p = blockIdx.x, t = threadIdx.x;
  int b = p >> 2, h = p & 3;
  lq[t] = qbuf[(b << 10) + (h << 8) + t];
  __syncthreads();
  const float* Kp = Kt + ((size_t)p << 16);
  float sc = 0.f;
#pragma unroll 4
  for (int d = 0; d < 256; d++) sc += lq[d] * Kp[(d << 8) + t];
  sc *= 0.0625f;
  float m = sc;
#pragma unroll
  for (int o = 32; o >= 1; o >>= 1) m = fmaxf(m, __shfl_xor(m, o, 64));
  if ((t & 63) == 0) red[t >> 6] = m;
  __syncthreads();
  m = fmaxf(fmaxf(red[0], red[1]), fmaxf(red[2], red[3]));
  float e = __expf(sc - m);
  float ss = e;
#pragma unroll
  for (int o = 32; o >= 1; o >>= 1) ss += __shfl_xor(ss, o, 64);
  if ((t & 63) == 0) red[4 + (t >> 6)] = ss;
  __syncthreads();
  ss = red[4] + red[5] + red[6] + red[7];
  latt[t] = e / ss;
  __syncthreads();
  const float* Vp = Vb + ((size_t)p << 16);
  float cv = 0.f;
#pragma unroll 4
  for (int s2 = 0; s2 < 256; s2++) cv += latt[s2] * Vp[(s2 << 8) + t];
  cr[(b << 10) + (h << 8) + t] = cv;
}

__global__ __launch_bounds__(256) void p1_kernel(
    const float* __restrict__ h1, const float* __restrict__ h2,
    const void* __restrict__ wih1, const void* __restrict__ whh1,
    const void* __restrict__ whh2, const void* __restrict__ wqkv,
    const void* __restrict__ wout, const int* __restrict__ flags,
    const float* __restrict__ b1c, const float* __restrict__ b2c,
    const float* __restrict__ bqF, const float* __restrict__ boutF,
    float* __restrict__ g1p, float* __restrict__ g2p,
    float* __restrict__ qbuf, float* __restrict__ out, int s) {
  __shared__ float smem[2048];
  int bi = blockIdx.x, t = threadIdx.x;
  if (bi < 1024) {
    int f5 = flags[5], f6 = flags[6], f10 = flags[10];
    int b = bi & 63, jt = bi >> 6;
    float4* s2 = (float4*)smem;
    float4* s1 = (float4*)(smem + 1024);
    s2[t] = ((const float4*)(h2 + (b << 10)))[t];
    s1[t] = ((const float4*)(h1 + (b << 10)))[t];
    __syncthreads();
    int j = (jt << 8) + t;
    size_t ra = (size_t)j * 2048, rb = (size_t)j * 1024;
    float a1 = 0.f, a3 = 0.f;
#pragma unroll 2
    for (int i = 0; i < 256; i++) {
      float4 A4 = ld4f(wih1, ra + 4 * i, f5);
      float4 B4 = ld4f(whh1, rb + 4 * i, f6);
      float4 C4 = ld4f(whh2, rb + 4 * i, f10);
      float4 x2 = s2[i], x1 = s1[i];
      a1 += x2.x * A4.x + x2.y * A4.y + x2.z * A4.z + x2.w * A4.w;
      a1 += x1.x * B4.x + x1.y * B4.y + x1.z * B4.z + x1.w * B4.w;
      a3 += x2.x * C4.x + x2.y * C4.y + x2.z * C4.z + x2.w * C4.w;
    }
    g1p[(b << 12) + j] = a1 + b1c[j];
    g2p[(b << 12) + j] = a3 + b2c[j];
  } else if (bi < 1280) {
    int f1 = flags[1];
    int idx = bi - 1024;
    int b = idx & 63, dt = idx >> 6;
    float4* s2 = (float4*)smem;
    s2[t] = ((const float4*)(h2 + (b << 10)))[t];
    __syncthreads();
    int col = (dt << 8) + t;
    size_t r = (size_t)col * 1024;
    float acc = 0.f;
#pragma unroll 4
    for (int i = 0; i < 256; i++) {
      float4 w4 = ld4f(wqkv, r + 4 * i, f1);
      float4 x = s2[i];
      acc += x.x * w4.x + x.y * w4.y + x.z * w4.z + x.w * w4.w;
    }
    qbuf[(b << 10) + col] = acc + bqF[col];
  } else {
    if (s == 0) return;
    int f13 = flags[13];
    int b = bi - 1280;
    float p[5] = {0.f, 0.f, 0.f, 0.f, 0.f};
#pragma unroll
    for (int k2 = 0; k2 < 4; k2++) {
      float hv = h2[(b << 10) + t + (k2 << 8)];
#pragma unroll
      for (int v = 0; v < 5; v++)
        p[v] += hv * ld1f(wout, (size_t)(v << 10) + t + (k2 << 8), f13);
    }
#pragma unroll
    for (int v = 0; v < 5; v++) smem[v * 256 + t] = p[v];
    __syncthreads();
    if (t < 5) {
      float acc = boutF[t];
      for (int i = 0; i < 256; i++) acc += smem[t * 256 + i];
      if (t >= 2) acc = sigm(acc);
      out[((s - 1) * 64 + b) * 5 + t] = acc;
    }
  }
}

__global__ __launch_bounds__(256) void oproj_kernel(
    const float* __restrict__ cr, const void* __restrict__ wo,
    const int* __restrict__ flags, const float* __restrict__ boF,
    float* __restrict__ cx) {
  __shared__ float lx[1024];
  int idx = blockIdx.x, b = idx & 63, dt = idx >> 6, t = threadIdx.x;
  ((float4*)lx)[t] = ((const float4*)(cr + (b << 10)))[t];
  __syncthreads();
  int f3 = flags[3];
  int col = (dt << 8) + t;
  size_t r = (size_t)col * 1024;
  float acc = 0.f;
#pragma unroll 4
  for (int i = 0; i < 256; i++) {
    float4 w4 = ld4f(wo, r + 4 * i, f3);
    float4 x = ((float4*)lx)[i];
    acc += x.x * w4.x + x.y * w4.y + x.z * w4.z + x.w * w4.w;
  }
  cx[(b << 10) + col] = acc + boF[col];
}

__global__ __launch_bounds__(256) void lstm_kernel(
    const float* __restrict__ xin, const void* __restrict__ Wg,
    const int* __restrict__ flags, int fidx, int rowStride, int colOff,
    const float* __restrict__ gpart, float* __restrict__ cbuf,
    float* __restrict__ hbuf) {
  __shared__ float lx[1024];
  int b = blockIdx.x >> 2, j0 = (blockIdx.x & 3) << 8;
  int t = threadIdx.x;
  ((float4*)lx)[t] = ((const float4*)(xin + (b << 10)))[t];
  __syncthreads();
  int bf = flags[fidx];
  int j = j0 + t;
  float g[4];
#pragma unroll
  for (int gi = 0; gi < 4; gi++) {
    size_t r = (size_t)((gi << 10) + j) * rowStride + colOff;
    float acc = 0.f;
#pragma unroll 4
    for (int i = 0; i < 256; i++) {
      float4 w4 = ld4f(Wg, r + 4 * i, bf);
      float4 x = ((float4*)lx)[i];
      acc += x.x * w4.x + x.y * w4.y + x.z * w4.z + x.w * w4.w;
    }
    g[gi] = gpart[(b << 12) + (gi << 10) + j] + acc;
  }
  float gi_ = sigm(g[0]);
  float gf_ = sigm(g[1]);
  float gg_ = tanhf(g[2]);
  float go_ = sigm(g[3]);
  float c = gf_ * cbuf[(b << 10) + j] + gi_ * gg_;
  cbuf[(b << 10) + j] = c;
  hbuf[(b << 10) + j] = go_ * tanhf(c);
}

// ===========================================================================
extern "C" void kernel_launch(void* const* d_in, const int* in_sizes, int n_in,
                              void* d_out, int out_size, void* d_ws, size_t ws_size,
                              hipStream_t stream) {
  float* out = (float*)d_out;
  float* W = (float*)d_ws;

  Ptrs pp;
  for (int i = 0; i < 15; i++) { pp.p[i] = d_in[i]; pp.n[i] = in_sizes[i]; }

  if (ws_size >= NWS_NEED) {
    // ------- R15 MFMA path (rebalanced 4-launch chain) -------
    float* h1    = W + NOFF_H1;
    float* c1    = W + NOFF_C1;
    float* h2    = W + NOFF_H2;
    float* c2    = W + NOFF_C2;
    ushort* h1h  = (ushort*)(W + NOFF_H1HI);
    ushort* h1l  = (ushort*)(W + NOFF_H1LO);
    ushort* h2h  = (ushort*)(W + NOFF_H2HI);
    ushort* h2l  = (ushort*)(W + NOFF_H2LO);
    ushort* crh  = (ushort*)(W + NOFF_CRHI);
    ushort* crl  = (ushort*)(W + NOFF_CRLO);
    float* qv    = W + NOFF_Q;
    float* g1p   = W + NOFF_G1P;
    float* g2p   = W + NOFF_G2P;
    float* b1c   = W + NOFF_B1C;
    float* b2c   = W + NOFF_B2C;
    float* bqF   = W + NOFF_BQ;
    float* boF   = W + NOFF_BO;
    float* boutF = W + NOFF_BOUT;
    int*   flags = (int*)(W + NOFF_FLAGS);
    float* scratch = W + NOFF_A1HI;           // Weff fp32 staging (overwritten by A1 conv)
    ushort* A1h = (ushort*)(W + NOFF_A1HI);
    ushort* A1l = (ushort*)(W + NOFF_A1LO);
    ushort* A2h = (ushort*)(W + NOFF_A2HI);
    ushort* A2l = (ushort*)(W + NOFF_A2LO);
    ushort* A3h = (ushort*)(W + NOFF_A3HI);
    ushort* A3l = (ushort*)(W + NOFF_A3LO);
    ushort* A5h = (ushort*)(W + NOFF_A5HI);
    ushort* A5l = (ushort*)(W + NOFF_A5LO);
    ushort* A6h = (ushort*)(W + NOFF_A6HI);
    ushort* A6l = (ushort*)(W + NOFF_A6LO);
    ushort* A4h = (ushort*)(W + NOFF_A4HI);
    ushort* A4l = (ushort*)(W + NOFF_A4LO);
    ushort* KtH = (ushort*)(W + NOFF_KTH);
    uchar*  KtL = (uchar*)(W + NOFF_KTL);
    ushort* VbH = (ushort*)(W + NOFF_VBH);
    uchar*  VbL = (uchar*)(W + NOFF_VBL);

    hipMemsetAsync(d_ws, 0, 393216ull * 4ull, stream);
    detect_kernel<<<1, 64, 0, stream>>>(pp, flags);
    bias_cvt<<<16, 256, 0, stream>>>(d_in[2], d_in[4], d_in[7], d_in[8],
                                     d_in[11], d_in[12], d_in[14], flags,
                                     bqF, boF, b1c, b2c, boutF);
    bias_fold<<<16, 256, 0, stream>>>(d_in[5], flags, boF, b1c);
    weff_gemm<<<dim3(16, 64), 256, 0, stream>>>(d_in[5], d_in[3], flags, scratch);
    kv_gemm<<<dim3(32, 256), 256, 0, stream>>>(d_in[0], d_in[1], flags, bqF,
                                               (void*)KtH, (void*)VbH, KtL, VbL, 1);
    // weight conversions (A5 from scratch FIRST, then A1 overwrites scratch)
    wconv_kernel<<<2048, 256, 0, stream>>>(scratch, flags, -1, 1024, 0, 8192, A5h, A5l);
    wconv_kernel<<<2048, 256, 0, stream>>>(d_in[5], flags, 5, 2048, 0, 8192, A1h, A1l);
    wconv_kernel<<<2048, 256, 0, stream>>>(d_in[6], flags, 6, 1024, 0, 8192, A2h, A2l);
    wconv_kernel<<<2048, 256, 0, stream>>>(d_in[10], flags, 10, 1024, 0, 8192, A3h, A3l);
    wconv_kernel<<<2048, 256, 0, stream>>>(d_in[9], flags, 9, 1024, 0, 8192, A6h, A6l);
    wconv_kernel<<<512, 256, 0, stream>>>(d_in[1], flags, 1, 1024, 0, 2048, A4h, A4l);

    for (int s = 0; s < S_LEN; s++) {
      p1_fused<<<224, 512, 0, stream>>>(h2, h2h, h2l, h1h, h1l,
                                        A4h, A4l, A1h, A1l, A2h, A2l, A3h, A3l,
                                        d_in[13], flags, bqF, boutF, b1c, b2c,
                                        qv, out, g1p, g2p, s);
      mega_kernel<<<256, 512, 0, stream>>>(qv, KtH, KtL, VbH, VbL, crh, crl);
      lstm_fused<<<256, 256, 0, stream>>>(crh, crl, A5h, A5l, g1p, c1, h1, h1h, h1l);
      lstm_fused<<<256, 256, 0, stream>>>(h1h, h1l, A6h, A6l, g2p, c2, h2, h2h, h2l);
    }
    outhead_kernel<<<64, 256, 0, stream>>>(h2, d_in[13], flags, boutF, out, 255);
  } else if (ws_size >= FWS_NEED) {
    // ---------------- round-5 fast path (proven) ----------------
    float* h1    = W + OFF_H1;
    float* c1    = W + OFF_C1;
    float* h2    = W + OFF_H2;
    float* c2    = W + OFF_C2;
    float* qv    = W + FOFF_QV;
    float* cr    = W + FOFF_CR;
    float* g1p   = W + FOFF_G1P;
    float* g2p   = W + FOFF_G2P;
    float* P     = W + FOFF_P;
    float* b1c   = W + FOFF_B1C;
    float* b2c   = W + FOFF_B2C;
    float* bqF   = W + FOFF_BQ;
    float* boF   = W + FOFF_BO;
    float* boutF = W + FOFF_BOUT;
    int*   flags = (int*)(W + FOFF_FLAGS);
    float* Weff  = W + FOFF_WEFF;
    float* Kt    = W + FOFF_KT;
    float* Vb    = W + FOFF_VB;

    hipMemsetAsync(d_ws, 0, 4 * 65536 * sizeof(float), stream);
    detect_kernel<<<1, 64, 0, stream>>>(pp, flags);
    bias_cvt<<<16, 256, 0, stream>>>(d_in[2], d_in[4], d_in[7], d_in[8],
                                     d_in[11], d_in[12], d_in[14], flags,
                                     bqF, boF, b1c, b2c, boutF);
    bias_fold<<<16, 256, 0, stream>>>(d_in[5], flags, boF, b1c);
    weff_gemm<<<dim3(16, 64), 256, 0, stream>>>(d_in[5], d_in[3], flags, Weff);
    kv_gemm<<<dim3(32, 256), 256, 0, stream>>>(d_in[0], d_in[1], flags, bqF,
                                               (void*)Kt, (void*)Vb, nullptr, nullptr, 0);

    for (int s = 0; s < S_LEN; s++) {
      p1_fast<<<208, 256, 0, stream>>>(h1, h2, d_in[5], d_in[6], d_in[10],
                                       d_in[1], d_in[13], flags, b1c, b2c,
                                       bqF, boutF, g1p, g2p, qv, out, s);
      attn_kernel<<<256, 256, 0, stream>>>(qv, Kt, Vb, cr);
      lstm_gemm<<<256, 256, 0, stream>>>(cr, Weff, flags, -1, P);
      lstm_ew<<<256, 256, 0, stream>>>(g1p, P, c1, h1);
      lstm_gemm<<<256, 256, 0, stream>>>(h1, d_in[9], flags, 9, P);
      lstm_ew<<<256, 256, 0, stream>>>(g2p, P, c2, h2);
    }
    outhead_kernel<<<64, 256, 0, stream>>>(h2, d_in[13], flags, boutF, out, 255);
  } else if (ws_size >= WS_NEED) {
    // ---------------- round-4 slow path (proven) ----------------
    float* h1    = W + OFF_H1;
    float* c1    = W + OFF_C1;
    float* h2    = W + OFF_H2;
    float* c2    = W + OFF_C2;
    float* qvb   = W + OFF_Q;
    float* cr    = W + OFF_CR;
    float* cx    = W + OFF_CX;
    float* g1p   = W + OFF_G1;
    float* g2p   = W + OFF_G2;
    float* b1c   = W + OFF_B1C;
    float* b2c   = W + OFF_B2C;
    float* bqF   = W + OFF_BQ;
    float* boF   = W + OFF_BO;
    float* boutF = W + OFF_BOUT;
    int*   flags = (int*)(W + OFF_FLAGS);
    float* Kt    = W + OFF_KT;
    float* Vb    = W + OFF_VB;

    hipMemsetAsync(d_ws, 0, 4 * 65536 * sizeof(float), stream);
    detect_kernel<<<1, 64, 0, stream>>>(pp, flags);
    bias_cvt<<<16, 256, 0, stream>>>(d_in[2], d_in[4], d_in[7], d_in[8],
                                     d_in[11], d_in[12], d_in[14], flags,
                                     bqF, boF, b1c, b2c, boutF);
    kv_gemm<<<dim3(32, 256), 256, 0, stream>>>(d_in[0], d_in[1], flags, bqF,
                                               (void*)Kt, (void*)Vb, nullptr, nullptr, 0);

    for (int s = 0; s < S_LEN; s++) {
      p1_kernel<<<1344, 256, 0, stream>>>(h1, h2, d_in[5], d_in[6], d_in[10],
                                          d_in[1], d_in[13], flags, b1c, b2c,
                                          bqF, boutF, g1p, g2p, qvb, out, s);
      attn_kernel<<<256, 256, 0, stream>>>(qvb, Kt, Vb, cr);
      oproj_kernel<<<256, 256, 0, stream>>>(cr, d_in[3], flags, boF, cx);
      lstm_kernel<<<256, 256, 0, stream>>>(cx, d_in[5], flags, 5, 2048, 1024, g1p, c1, h1);
      lstm_kernel<<<256, 256, 0, stream>>>(h1, d_in[9], flags, 9, 1024, 0, g2p, c2, h2);
    }
    outhead_kernel<<<64, 256, 0, stream>>>(h2, d_in[13], flags, boutF, out, 255);
  }
}